// Round 8
// baseline (60.418 us; speedup 1.0000x reference)
//
#include <hip/hip_runtime.h>
#include <hip/hip_bf16.h>
#include <math.h>
#include <stdint.h>

#define N_RAYS    32768
#define N_SAMPLES (N_RAYS * 32)
#define THRESH 0.0001f
#define TBL_OFF  (16u * 1024u * 1024u)   // frag table lives after smp[] in d_ws
#define N_FRAGS  22

typedef __attribute__((ext_vector_type(8))) __bf16 bf16x8;
typedef __attribute__((ext_vector_type(4))) float  f32x4;
typedef float f4a __attribute__((ext_vector_type(4), aligned(4)));

union FragU { __hip_bfloat162 h2[4]; uint32_t w[4]; bf16x8 v; };
union RecU  { bf16x8 v; f32x4 f; uint4 u; };

__device__ inline __hip_bfloat162 pk2(float lo, float hi) {
    float2 t; t.x = lo; t.y = hi;
    return __float22bfloat162_rn(t);
}

__device__ inline bf16x8 pack8(const float* vals) {
    FragU u;
    u.h2[0] = pk2(vals[0], vals[1]);
    u.h2[1] = pk2(vals[2], vals[3]);
    u.h2[2] = pk2(vals[4], vals[5]);
    u.h2[3] = pk2(vals[6], vals[7]);
    return u.v;
}

__device__ inline float rcp_fast(float x) {
    float r;
    asm("v_rcp_f32 %0, %1" : "=v"(r) : "v"(x));
    return r;
}
__device__ inline float sigmoid_fast(float x) { return rcp_fast(1.0f + __expf(-x)); }
__device__ inline float softplus_fast(float x) {
    const float e = __expf(-fabsf(x));
    return fmaxf(x, 0.0f) + __logf(1.0f + e);
}

// ---------------------------------------------------------------------------
// Setup kernel (1 block): build all per-lane weight fragments ONCE, store to
// d_ws table [fid][lane] as 16B records. Eliminates the per-wave scattered
// gather prologue (120 address-divergent loads/wave) from the main kernel.
// Frag ids: A1:0-3, A2[t][c]:4+2t+c, Ar1a:8-11, Ar1b:12-15, Ar2:16-17,
//           Ar2f:18, b2i(f32):19-20, arinit(f32):21
// ---------------------------------------------------------------------------
__global__ __launch_bounds__(256) void nerf_build_frags(
    const float* __restrict__ w1,  const float* __restrict__ b1,
    const float* __restrict__ w2,  const float* __restrict__ b2,
    const float* __restrict__ w_sigma, const float* __restrict__ b_sigma,
    const float* __restrict__ w_rgb1,  const float* __restrict__ b_rgb1,
    const float* __restrict__ w_rgb2,  const float* __restrict__ b_rgb2,
    uint4* __restrict__ tbl)
{
    const int wid  = threadIdx.x >> 6;
    const int lane = threadIdx.x & 63;
    const int g    = lane >> 4;
    const int sl   = lane & 15;
    RecU rec;

    if (wid == 0) {
        #pragma unroll
        for (int t = 0; t < 4; ++t) {      // A1 = [w1;b1]^T (g==0, q=0..3)
            float v[8] = {0,0,0,0,0,0,0,0};
            if (g == 0) {
                const int j = t*16 + sl;
                v[0] = w1[j]; v[1] = w1[64+j]; v[2] = w1[128+j]; v[3] = b1[j];
            }
            rec.v = pack8(v); tbl[t*64 + lane] = rec.u;
        }
        #pragma unroll
        for (int t = 0; t < 2; ++t)        // A2 = w2^T, permuted k
            #pragma unroll
            for (int c = 0; c < 2; ++c) {
                float v[8];
                #pragma unroll
                for (int q = 0; q < 8; ++q) {
                    const int j = 16*(2*c + (q>>2)) + 4*g + (q&3);
                    v[q] = w2[j*32 + t*16 + sl];
                }
                rec.v = pack8(v); tbl[(4 + 2*t + c)*64 + lane] = rec.u;
            }
    } else if (wid == 1) {
        #pragma unroll
        for (int t = 0; t < 4; ++t) {      // Ar1a = w_rgb1^T (feats), permuted k
            float v[8];
            #pragma unroll
            for (int q = 0; q < 8; ++q) {
                const int f = 16*(q>>2) + 4*g + (q&3);
                v[q] = w_rgb1[f*64 + t*16 + sl];
            }
            rec.v = pack8(v); tbl[(8 + t)*64 + lane] = rec.u;
        }
        #pragma unroll
        for (int t = 0; t < 4; ++t) {      // Ar1b = dirs rows + b_rgb1 (g==0)
            float v[8] = {0,0,0,0,0,0,0,0};
            if (g == 0) {
                const int j = t*16 + sl;
                v[0] = w_rgb1[32*64 + j]; v[1] = w_rgb1[33*64 + j];
                v[2] = w_rgb1[34*64 + j]; v[3] = b_rgb1[j];
            }
            rec.v = pack8(v); tbl[(12 + t)*64 + lane] = rec.u;
        }
    } else if (wid == 2) {
        #pragma unroll
        for (int c = 0; c < 2; ++c) {      // Ar2 = w_rgb2^T rows 0..2, permuted k
            float v[8];
            #pragma unroll
            for (int q = 0; q < 8; ++q) {
                const int hh = 16*(2*c + (q>>2)) + 4*g + (q&3);
                v[q] = (sl < 3) ? w_rgb2[hh*3 + sl] : 0.0f;
            }
            rec.v = pack8(v); tbl[(16 + c)*64 + lane] = rec.u;
        }
        {                                  // Ar2f = w_sigma on row m=3
            float v[8];
            #pragma unroll
            for (int q = 0; q < 8; ++q) {
                const int f = 16*(q>>2) + 4*g + (q&3);
                v[q] = (sl == 3) ? w_sigma[f] : 0.0f;
            }
            rec.v = pack8(v); tbl[18*64 + lane] = rec.u;
        }
        #pragma unroll
        for (int t = 0; t < 2; ++t) {      // b2i (f32x4, C-operand layout m=4g+r)
            #pragma unroll
            for (int r = 0; r < 4; ++r) rec.f[r] = b2[16*t + 4*g + r];
            tbl[(19 + t)*64 + lane] = rec.u;
        }
        {                                  // arinit (f32x4, uniform)
            rec.f[0] = b_rgb2[0]; rec.f[1] = b_rgb2[1];
            rec.f[2] = b_rgb2[2]; rec.f[3] = b_sigma[0];
            tbl[21*64 + lane] = rec.u;
        }
    }
}

// ---------------------------------------------------------------------------
// Main MFMA MLP. One wave = 128 contiguous samples (4 pairs, dual-stream).
// Prologue = 22 coalesced dwordx4 loads from the frag table.
// D layout: n=lane&15, m=4*(lane>>4)+reg; B k-map == previous D layout.
// ---------------------------------------------------------------------------
__global__ __launch_bounds__(256, 4) void nerf_mlp_mfma(
    const float* __restrict__ samples,   // (N_SAMPLES, 7)
    const uint4* __restrict__ tbl,       // [22][64] frag table
    float4* __restrict__ out)            // (N_SAMPLES): tau, r, g, b
{
    const int lane = threadIdx.x & 63;
    const int g    = lane >> 4;
    const int sl   = lane & 15;
    const int wgid = (blockIdx.x * blockDim.x + threadIdx.x) >> 6;
    const int base0 = wgid * 128;

    // ---- pair-0 sample loads issued first
    f4a sa[4][2], sb[4][2];
    {
        const float* sp0 = samples + (size_t)(base0 + sl) * 7;
        const float* sp1 = samples + (size_t)(base0 + 16 + sl) * 7;
        sa[0][0] = *(const f4a*)sp0;  sb[0][0] = *(const f4a*)(sp0 + 3);
        sa[0][1] = *(const f4a*)sp1;  sb[0][1] = *(const f4a*)(sp1 + 3);
    }

    // ---- coalesced fragment loads
    bf16x8 A1[4], A2[2][2], Ar1a[4], Ar1b[4], Ar2[2], Ar2f;
    f32x4 b2i[2], arinit;
    {
        RecU r_;
        #pragma unroll
        for (int t = 0; t < 4; ++t) { r_.u = tbl[t*64 + lane];       A1[t]   = r_.v; }
        #pragma unroll
        for (int t = 0; t < 2; ++t)
            #pragma unroll
            for (int c = 0; c < 2; ++c) { r_.u = tbl[(4+2*t+c)*64 + lane]; A2[t][c] = r_.v; }
        #pragma unroll
        for (int t = 0; t < 4; ++t) { r_.u = tbl[(8+t)*64 + lane];   Ar1a[t] = r_.v; }
        #pragma unroll
        for (int t = 0; t < 4; ++t) { r_.u = tbl[(12+t)*64 + lane];  Ar1b[t] = r_.v; }
        #pragma unroll
        for (int c = 0; c < 2; ++c) { r_.u = tbl[(16+c)*64 + lane];  Ar2[c]  = r_.v; }
        r_.u = tbl[18*64 + lane]; Ar2f = r_.v;
        r_.u = tbl[19*64 + lane]; b2i[0] = r_.f;
        r_.u = tbl[20*64 + lane]; b2i[1] = r_.f;
        r_.u = tbl[21*64 + lane]; arinit = r_.f;
    }

    const float biasone = (g == 0) ? 1.0f : 0.0f;
    const f32x4 zero4 = {0.f, 0.f, 0.f, 0.f};

    #pragma unroll
    for (int it = 0; it < 4; ++it) {
        if (it < 3) {   // prefetch next pair
            const int nb = base0 + (it + 1) * 32;
            const float* sp0 = samples + (size_t)(nb + sl) * 7;
            const float* sp1 = samples + (size_t)(nb + 16 + sl) * 7;
            sa[it+1][0] = *(const f4a*)sp0;  sb[it+1][0] = *(const f4a*)(sp0 + 3);
            sa[it+1][1] = *(const f4a*)sp1;  sb[it+1][1] = *(const f4a*)(sp1 + 3);
        }

        FragU b1u[2], bd[2];
        #pragma unroll
        for (int s = 0; s < 2; ++s) {
            b1u[s].h2[0] = pk2(sa[it][s].x, sa[it][s].y);
            b1u[s].h2[1] = pk2(sa[it][s].z, biasone);
            b1u[s].w[2] = 0; b1u[s].w[3] = 0;
            bd[s].h2[0]  = pk2(sb[it][s].x, sb[it][s].y);
            bd[s].h2[1]  = pk2(sb[it][s].z, biasone);
            bd[s].w[2] = 0; bd[s].w[3] = 0;
        }

        // layer1
        f32x4 accL1[2][4];
        #pragma unroll
        for (int t = 0; t < 4; ++t)
            #pragma unroll
            for (int s = 0; s < 2; ++s)
                accL1[s][t] = __builtin_amdgcn_mfma_f32_16x16x32_bf16(A1[t], b1u[s].v, zero4, 0,0,0);

        FragU B2c[2][2];
        #pragma unroll
        for (int s = 0; s < 2; ++s)
            #pragma unroll
            for (int c = 0; c < 2; ++c) {
                B2c[s][c].h2[0] = pk2(fmaxf(accL1[s][2*c  ][0],0.f), fmaxf(accL1[s][2*c  ][1],0.f));
                B2c[s][c].h2[1] = pk2(fmaxf(accL1[s][2*c  ][2],0.f), fmaxf(accL1[s][2*c  ][3],0.f));
                B2c[s][c].h2[2] = pk2(fmaxf(accL1[s][2*c+1][0],0.f), fmaxf(accL1[s][2*c+1][1],0.f));
                B2c[s][c].h2[3] = pk2(fmaxf(accL1[s][2*c+1][2],0.f), fmaxf(accL1[s][2*c+1][3],0.f));
            }

        // layer2 (+b2 via C)
        f32x4 accL2[2][2];
        #pragma unroll
        for (int t = 0; t < 2; ++t)
            #pragma unroll
            for (int s = 0; s < 2; ++s) {
                accL2[s][t] = __builtin_amdgcn_mfma_f32_16x16x32_bf16(A2[t][0], B2c[s][0].v, b2i[t], 0,0,0);
                accL2[s][t] = __builtin_amdgcn_mfma_f32_16x16x32_bf16(A2[t][1], B2c[s][1].v, accL2[s][t], 0,0,0);
            }
        FragU Bf[2];
        #pragma unroll
        for (int s = 0; s < 2; ++s) {
            Bf[s].h2[0] = pk2(accL2[s][0][0], accL2[s][0][1]);
            Bf[s].h2[1] = pk2(accL2[s][0][2], accL2[s][0][3]);
            Bf[s].h2[2] = pk2(accL2[s][1][0], accL2[s][1][1]);
            Bf[s].h2[3] = pk2(accL2[s][1][2], accL2[s][1][3]);
        }

        // rgb1
        f32x4 ah[2][4];
        #pragma unroll
        for (int t = 0; t < 4; ++t)
            #pragma unroll
            for (int s = 0; s < 2; ++s) {
                ah[s][t] = __builtin_amdgcn_mfma_f32_16x16x32_bf16(Ar1a[t], Bf[s].v, zero4, 0,0,0);
                ah[s][t] = __builtin_amdgcn_mfma_f32_16x16x32_bf16(Ar1b[t], bd[s].v, ah[s][t], 0,0,0);
            }
        FragU Bh[2][2];
        #pragma unroll
        for (int s = 0; s < 2; ++s)
            #pragma unroll
            for (int c = 0; c < 2; ++c) {
                Bh[s][c].h2[0] = pk2(fmaxf(ah[s][2*c  ][0],0.f), fmaxf(ah[s][2*c  ][1],0.f));
                Bh[s][c].h2[1] = pk2(fmaxf(ah[s][2*c  ][2],0.f), fmaxf(ah[s][2*c  ][3],0.f));
                Bh[s][c].h2[2] = pk2(fmaxf(ah[s][2*c+1][0],0.f), fmaxf(ah[s][2*c+1][1],0.f));
                Bh[s][c].h2[3] = pk2(fmaxf(ah[s][2*c+1][2],0.f), fmaxf(ah[s][2*c+1][3],0.f));
            }

        // rgb2 (+sigma m=3)
        f32x4 ar[2];
        #pragma unroll
        for (int s = 0; s < 2; ++s) {
            ar[s] = __builtin_amdgcn_mfma_f32_16x16x32_bf16(Ar2[0], Bh[s][0].v, arinit, 0,0,0);
            ar[s] = __builtin_amdgcn_mfma_f32_16x16x32_bf16(Ar2[1], Bh[s][1].v, ar[s], 0,0,0);
            ar[s] = __builtin_amdgcn_mfma_f32_16x16x32_bf16(Ar2f,   Bf[s].v,    ar[s], 0,0,0);
        }

        #pragma unroll
        for (int s = 0; s < 2; ++s) {
            const float rr    = sigmoid_fast(ar[s][0]);
            const float gg    = sigmoid_fast(ar[s][1]);
            const float bb    = sigmoid_fast(ar[s][2]);
            const float sigma = softplus_fast(ar[s][3]);
            const float tau   = sigma * sb[it][s].w;
            if (g == 0) out[base0 + it * 32 + s * 16 + sl] = make_float4(tau, rr, gg, bb);
        }
    }
}

// ---------------------------------------------------------------------------
// Kernel 2: one wave per ray — scan tau, gate, reduce.
// ---------------------------------------------------------------------------
__global__ __launch_bounds__(256) void nerf_render_kernel(
    const float4* __restrict__ smp,
    const int*    __restrict__ packing,
    const float*  __restrict__ bg,
    float*        __restrict__ out)
{
    const int gtid = blockIdx.x * blockDim.x + threadIdx.x;
    const int ray  = gtid >> 6;
    const int lane = threadIdx.x & 63;
    if (ray >= N_RAYS) return;

    const int start = packing[2 * ray];
    const int count = packing[2 * ray + 1];

    float tau = 0.0f, r = 0.0f, g = 0.0f, b = 0.0f;
    if (lane < count) {
        const float4 v = smp[start + lane];
        tau = v.x; r = v.y; g = v.z; b = v.w;
    }

    float incl = tau;
    #pragma unroll
    for (int off = 1; off < 64; off <<= 1) {
        const float v = __shfl_up(incl, off, 64);
        if (lane >= off) incl += v;
    }
    const float c_excl = incl - tau;

    const float T     = __expf(-c_excl);
    const float alpha = 1.0f - __expf(-tau);
    float w = (lane < count && T > THRESH) ? T * alpha : 0.0f;

    float cr = r * w, cg = g * w, cb = b * w;

    #pragma unroll
    for (int off = 32; off > 0; off >>= 1) {
        cr += __shfl_down(cr, off, 64);
        cg += __shfl_down(cg, off, 64);
        cb += __shfl_down(cb, off, 64);
        w  += __shfl_down(w,  off, 64);
    }

    if (lane == 0) {
        out[ray * 3 + 0] = cr + bg[0] * (1.0f - w);
        out[ray * 3 + 1] = cg + bg[1] * (1.0f - w);
        out[ray * 3 + 2] = cb + bg[2] * (1.0f - w);
    }
}

extern "C" void kernel_launch(void* const* d_in, const int* in_sizes, int n_in,
                              void* d_out, int out_size, void* d_ws, size_t ws_size,
                              hipStream_t stream) {
    const float* samples  = (const float*)d_in[0];
    const int*   packing  = (const int*)  d_in[1];
    const float* w1       = (const float*)d_in[3];
    const float* b1       = (const float*)d_in[4];
    const float* w2       = (const float*)d_in[5];
    const float* b2       = (const float*)d_in[6];
    const float* w_sigma  = (const float*)d_in[7];
    const float* b_sigma  = (const float*)d_in[8];
    const float* w_rgb1   = (const float*)d_in[9];
    const float* b_rgb1   = (const float*)d_in[10];
    const float* w_rgb2   = (const float*)d_in[11];
    const float* b_rgb2   = (const float*)d_in[12];
    const float* bg       = (const float*)d_in[13];

    float4* smp = (float4*)d_ws;                         // 16 MiB
    uint4*  tbl = (uint4*)((char*)d_ws + TBL_OFF);       // 22.5 KiB frag table
    float*  out = (float*)d_out;

    nerf_build_frags<<<1, 256, 0, stream>>>(
        w1, b1, w2, b2, w_sigma, b_sigma,
        w_rgb1, b_rgb1, w_rgb2, b_rgb2, tbl);

    nerf_mlp_mfma<<<2048, 256, 0, stream>>>(samples, tbl, (float4*)smp);

    nerf_render_kernel<<<(N_RAYS * 64) / 256, 256, 0, stream>>>(smp, packing, bg, out);
}

// Round 9
// 49.350 us; speedup vs baseline: 1.2243x; 1.2243x over previous
//
#include <hip/hip_runtime.h>
#include <hip/hip_bf16.h>
#include <math.h>
#include <stdint.h>

#define N_RAYS    32768
#define N_SAMPLES (N_RAYS * 32)
#define THRESH 0.0001f
#define TBL_OFF  (16u * 1024u * 1024u)   // frag table lives after smp[] in d_ws

typedef __attribute__((ext_vector_type(8))) __bf16 bf16x8;
typedef __attribute__((ext_vector_type(4))) float  f32x4;
typedef float f4a __attribute__((ext_vector_type(4), aligned(4)));

union FragU { __hip_bfloat162 h2[4]; uint32_t w[4]; bf16x8 v; };
union RecU  { bf16x8 v; f32x4 f; uint4 u; };

__device__ inline __hip_bfloat162 pk2(float lo, float hi) {
    float2 t; t.x = lo; t.y = hi;
    return __float22bfloat162_rn(t);
}

__device__ inline bf16x8 pack8(const float* vals) {
    FragU u;
    u.h2[0] = pk2(vals[0], vals[1]);
    u.h2[1] = pk2(vals[2], vals[3]);
    u.h2[2] = pk2(vals[4], vals[5]);
    u.h2[3] = pk2(vals[6], vals[7]);
    return u.v;
}

__device__ inline float rcp_fast(float x) {
    float r;
    asm("v_rcp_f32 %0, %1" : "=v"(r) : "v"(x));
    return r;
}
__device__ inline float sigmoid_fast(float x) { return rcp_fast(1.0f + __expf(-x)); }
__device__ inline float softplus_fast(float x) {
    const float e = __expf(-fabsf(x));
    return fmaxf(x, 0.0f) + __logf(1.0f + e);
}

// ---------------------------------------------------------------------------
// Setup kernel (1 block): build all per-lane weight fragments once into d_ws.
// Frag ids: A1:0-3, A2[t][c]:4+2t+c, Ar1a:8-11, Ar1b:12-15, Ar2:16-17,
//           Ar2f:18, b2i(f32):19-20, arinit(f32):21
// ---------------------------------------------------------------------------
__global__ __launch_bounds__(256) void nerf_build_frags(
    const float* __restrict__ w1,  const float* __restrict__ b1,
    const float* __restrict__ w2,  const float* __restrict__ b2,
    const float* __restrict__ w_sigma, const float* __restrict__ b_sigma,
    const float* __restrict__ w_rgb1,  const float* __restrict__ b_rgb1,
    const float* __restrict__ w_rgb2,  const float* __restrict__ b_rgb2,
    uint4* __restrict__ tbl)
{
    const int wid  = threadIdx.x >> 6;
    const int lane = threadIdx.x & 63;
    const int g    = lane >> 4;
    const int sl   = lane & 15;
    RecU rec;

    if (wid == 0) {
        #pragma unroll
        for (int t = 0; t < 4; ++t) {      // A1 = [w1;b1]^T (g==0, q=0..3)
            float v[8] = {0,0,0,0,0,0,0,0};
            if (g == 0) {
                const int j = t*16 + sl;
                v[0] = w1[j]; v[1] = w1[64+j]; v[2] = w1[128+j]; v[3] = b1[j];
            }
            rec.v = pack8(v); tbl[t*64 + lane] = rec.u;
        }
        #pragma unroll
        for (int t = 0; t < 2; ++t)        // A2 = w2^T, permuted k
            #pragma unroll
            for (int c = 0; c < 2; ++c) {
                float v[8];
                #pragma unroll
                for (int q = 0; q < 8; ++q) {
                    const int j = 16*(2*c + (q>>2)) + 4*g + (q&3);
                    v[q] = w2[j*32 + t*16 + sl];
                }
                rec.v = pack8(v); tbl[(4 + 2*t + c)*64 + lane] = rec.u;
            }
    } else if (wid == 1) {
        #pragma unroll
        for (int t = 0; t < 4; ++t) {      // Ar1a = w_rgb1^T (feats), permuted k
            float v[8];
            #pragma unroll
            for (int q = 0; q < 8; ++q) {
                const int f = 16*(q>>2) + 4*g + (q&3);
                v[q] = w_rgb1[f*64 + t*16 + sl];
            }
            rec.v = pack8(v); tbl[(8 + t)*64 + lane] = rec.u;
        }
        #pragma unroll
        for (int t = 0; t < 4; ++t) {      // Ar1b = dirs rows + b_rgb1 (g==0)
            float v[8] = {0,0,0,0,0,0,0,0};
            if (g == 0) {
                const int j = t*16 + sl;
                v[0] = w_rgb1[32*64 + j]; v[1] = w_rgb1[33*64 + j];
                v[2] = w_rgb1[34*64 + j]; v[3] = b_rgb1[j];
            }
            rec.v = pack8(v); tbl[(12 + t)*64 + lane] = rec.u;
        }
    } else if (wid == 2) {
        #pragma unroll
        for (int c = 0; c < 2; ++c) {      // Ar2 = w_rgb2^T rows 0..2, permuted k
            float v[8];
            #pragma unroll
            for (int q = 0; q < 8; ++q) {
                const int hh = 16*(2*c + (q>>2)) + 4*g + (q&3);
                v[q] = (sl < 3) ? w_rgb2[hh*3 + sl] : 0.0f;
            }
            rec.v = pack8(v); tbl[(16 + c)*64 + lane] = rec.u;
        }
        {                                  // Ar2f = w_sigma on row m=3
            float v[8];
            #pragma unroll
            for (int q = 0; q < 8; ++q) {
                const int f = 16*(q>>2) + 4*g + (q&3);
                v[q] = (sl == 3) ? w_sigma[f] : 0.0f;
            }
            rec.v = pack8(v); tbl[18*64 + lane] = rec.u;
        }
        #pragma unroll
        for (int t = 0; t < 2; ++t) {      // b2i (f32x4, C-operand layout m=4g+r)
            #pragma unroll
            for (int r = 0; r < 4; ++r) rec.f[r] = b2[16*t + 4*g + r];
            tbl[(19 + t)*64 + lane] = rec.u;
        }
        {                                  // arinit (f32x4, uniform)
            rec.f[0] = b_rgb2[0]; rec.f[1] = b_rgb2[1];
            rec.f[2] = b_rgb2[2]; rec.f[3] = b_sigma[0];
            tbl[21*64 + lane] = rec.u;
        }
    }
}

// ---------------------------------------------------------------------------
// Main MFMA MLP. One wave = 128 contiguous samples (4 pairs, dual-stream).
// waves_per_eu=3 -> ~170-reg unified budget: fits all live state (frags ~88 +
// dual-stream accs) with ZERO spills, 3 blocks/CU resident.
// D layout: n=lane&15, m=4*(lane>>4)+reg; B k-map == previous D layout.
// ---------------------------------------------------------------------------
__global__ __launch_bounds__(256, 3) void nerf_mlp_mfma(
    const float* __restrict__ samples,   // (N_SAMPLES, 7)
    const uint4* __restrict__ tbl,       // [22][64] frag table
    float4* __restrict__ out)            // (N_SAMPLES): tau, r, g, b
{
    const int lane = threadIdx.x & 63;
    const int g    = lane >> 4;
    const int sl   = lane & 15;
    const int wgid = (blockIdx.x * blockDim.x + threadIdx.x) >> 6;
    const int base0 = wgid * 128;

    // ---- pair-0 sample loads issued first
    f4a sa[4][2], sb[4][2];
    {
        const float* sp0 = samples + (size_t)(base0 + sl) * 7;
        const float* sp1 = samples + (size_t)(base0 + 16 + sl) * 7;
        sa[0][0] = *(const f4a*)sp0;  sb[0][0] = *(const f4a*)(sp0 + 3);
        sa[0][1] = *(const f4a*)sp1;  sb[0][1] = *(const f4a*)(sp1 + 3);
    }

    // ---- coalesced fragment loads (L2-resident table)
    bf16x8 A1[4], A2[2][2], Ar1a[4], Ar1b[4], Ar2[2], Ar2f;
    f32x4 b2i[2], arinit;
    {
        RecU r_;
        #pragma unroll
        for (int t = 0; t < 4; ++t) { r_.u = tbl[t*64 + lane];       A1[t]   = r_.v; }
        #pragma unroll
        for (int t = 0; t < 2; ++t)
            #pragma unroll
            for (int c = 0; c < 2; ++c) { r_.u = tbl[(4+2*t+c)*64 + lane]; A2[t][c] = r_.v; }
        #pragma unroll
        for (int t = 0; t < 4; ++t) { r_.u = tbl[(8+t)*64 + lane];   Ar1a[t] = r_.v; }
        #pragma unroll
        for (int t = 0; t < 4; ++t) { r_.u = tbl[(12+t)*64 + lane];  Ar1b[t] = r_.v; }
        #pragma unroll
        for (int c = 0; c < 2; ++c) { r_.u = tbl[(16+c)*64 + lane];  Ar2[c]  = r_.v; }
        r_.u = tbl[18*64 + lane]; Ar2f = r_.v;
        r_.u = tbl[19*64 + lane]; b2i[0] = r_.f;
        r_.u = tbl[20*64 + lane]; b2i[1] = r_.f;
        r_.u = tbl[21*64 + lane]; arinit = r_.f;
    }

    const float biasone = (g == 0) ? 1.0f : 0.0f;
    const f32x4 zero4 = {0.f, 0.f, 0.f, 0.f};

    #pragma unroll
    for (int it = 0; it < 4; ++it) {
        if (it < 3) {   // prefetch next pair
            const int nb = base0 + (it + 1) * 32;
            const float* sp0 = samples + (size_t)(nb + sl) * 7;
            const float* sp1 = samples + (size_t)(nb + 16 + sl) * 7;
            sa[it+1][0] = *(const f4a*)sp0;  sb[it+1][0] = *(const f4a*)(sp0 + 3);
            sa[it+1][1] = *(const f4a*)sp1;  sb[it+1][1] = *(const f4a*)(sp1 + 3);
        }

        FragU b1u[2], bd[2];
        #pragma unroll
        for (int s = 0; s < 2; ++s) {
            b1u[s].h2[0] = pk2(sa[it][s].x, sa[it][s].y);
            b1u[s].h2[1] = pk2(sa[it][s].z, biasone);
            b1u[s].w[2] = 0; b1u[s].w[3] = 0;
            bd[s].h2[0]  = pk2(sb[it][s].x, sb[it][s].y);
            bd[s].h2[1]  = pk2(sb[it][s].z, biasone);
            bd[s].w[2] = 0; bd[s].w[3] = 0;
        }

        // layer1
        f32x4 accL1[2][4];
        #pragma unroll
        for (int t = 0; t < 4; ++t)
            #pragma unroll
            for (int s = 0; s < 2; ++s)
                accL1[s][t] = __builtin_amdgcn_mfma_f32_16x16x32_bf16(A1[t], b1u[s].v, zero4, 0,0,0);

        FragU B2c[2][2];
        #pragma unroll
        for (int s = 0; s < 2; ++s)
            #pragma unroll
            for (int c = 0; c < 2; ++c) {
                B2c[s][c].h2[0] = pk2(fmaxf(accL1[s][2*c  ][0],0.f), fmaxf(accL1[s][2*c  ][1],0.f));
                B2c[s][c].h2[1] = pk2(fmaxf(accL1[s][2*c  ][2],0.f), fmaxf(accL1[s][2*c  ][3],0.f));
                B2c[s][c].h2[2] = pk2(fmaxf(accL1[s][2*c+1][0],0.f), fmaxf(accL1[s][2*c+1][1],0.f));
                B2c[s][c].h2[3] = pk2(fmaxf(accL1[s][2*c+1][2],0.f), fmaxf(accL1[s][2*c+1][3],0.f));
            }

        // layer2 (+b2 via C)
        f32x4 accL2[2][2];
        #pragma unroll
        for (int t = 0; t < 2; ++t)
            #pragma unroll
            for (int s = 0; s < 2; ++s) {
                accL2[s][t] = __builtin_amdgcn_mfma_f32_16x16x32_bf16(A2[t][0], B2c[s][0].v, b2i[t], 0,0,0);
                accL2[s][t] = __builtin_amdgcn_mfma_f32_16x16x32_bf16(A2[t][1], B2c[s][1].v, accL2[s][t], 0,0,0);
            }
        FragU Bf[2];
        #pragma unroll
        for (int s = 0; s < 2; ++s) {
            Bf[s].h2[0] = pk2(accL2[s][0][0], accL2[s][0][1]);
            Bf[s].h2[1] = pk2(accL2[s][0][2], accL2[s][0][3]);
            Bf[s].h2[2] = pk2(accL2[s][1][0], accL2[s][1][1]);
            Bf[s].h2[3] = pk2(accL2[s][1][2], accL2[s][1][3]);
        }

        // rgb1
        f32x4 ah[2][4];
        #pragma unroll
        for (int t = 0; t < 4; ++t)
            #pragma unroll
            for (int s = 0; s < 2; ++s) {
                ah[s][t] = __builtin_amdgcn_mfma_f32_16x16x32_bf16(Ar1a[t], Bf[s].v, zero4, 0,0,0);
                ah[s][t] = __builtin_amdgcn_mfma_f32_16x16x32_bf16(Ar1b[t], bd[s].v, ah[s][t], 0,0,0);
            }
        FragU Bh[2][2];
        #pragma unroll
        for (int s = 0; s < 2; ++s)
            #pragma unroll
            for (int c = 0; c < 2; ++c) {
                Bh[s][c].h2[0] = pk2(fmaxf(ah[s][2*c  ][0],0.f), fmaxf(ah[s][2*c  ][1],0.f));
                Bh[s][c].h2[1] = pk2(fmaxf(ah[s][2*c  ][2],0.f), fmaxf(ah[s][2*c  ][3],0.f));
                Bh[s][c].h2[2] = pk2(fmaxf(ah[s][2*c+1][0],0.f), fmaxf(ah[s][2*c+1][1],0.f));
                Bh[s][c].h2[3] = pk2(fmaxf(ah[s][2*c+1][2],0.f), fmaxf(ah[s][2*c+1][3],0.f));
            }

        // rgb2 (+sigma m=3)
        f32x4 ar[2];
        #pragma unroll
        for (int s = 0; s < 2; ++s) {
            ar[s] = __builtin_amdgcn_mfma_f32_16x16x32_bf16(Ar2[0], Bh[s][0].v, arinit, 0,0,0);
            ar[s] = __builtin_amdgcn_mfma_f32_16x16x32_bf16(Ar2[1], Bh[s][1].v, ar[s], 0,0,0);
            ar[s] = __builtin_amdgcn_mfma_f32_16x16x32_bf16(Ar2f,   Bf[s].v,    ar[s], 0,0,0);
        }

        #pragma unroll
        for (int s = 0; s < 2; ++s) {
            const float rr    = sigmoid_fast(ar[s][0]);
            const float gg    = sigmoid_fast(ar[s][1]);
            const float bb    = sigmoid_fast(ar[s][2]);
            const float sigma = softplus_fast(ar[s][3]);
            const float tau   = sigma * sb[it][s].w;
            if (g == 0) out[base0 + it * 32 + s * 16 + sl] = make_float4(tau, rr, gg, bb);
        }
    }
}

// ---------------------------------------------------------------------------
// Kernel 2: one wave per ray — scan tau, gate, reduce.
// ---------------------------------------------------------------------------
__global__ __launch_bounds__(256) void nerf_render_kernel(
    const float4* __restrict__ smp,
    const int*    __restrict__ packing,
    const float*  __restrict__ bg,
    float*        __restrict__ out)
{
    const int gtid = blockIdx.x * blockDim.x + threadIdx.x;
    const int ray  = gtid >> 6;
    const int lane = threadIdx.x & 63;
    if (ray >= N_RAYS) return;

    const int start = packing[2 * ray];
    const int count = packing[2 * ray + 1];

    float tau = 0.0f, r = 0.0f, g = 0.0f, b = 0.0f;
    if (lane < count) {
        const float4 v = smp[start + lane];
        tau = v.x; r = v.y; g = v.z; b = v.w;
    }

    float incl = tau;
    #pragma unroll
    for (int off = 1; off < 64; off <<= 1) {
        const float v = __shfl_up(incl, off, 64);
        if (lane >= off) incl += v;
    }
    const float c_excl = incl - tau;

    const float T     = __expf(-c_excl);
    const float alpha = 1.0f - __expf(-tau);
    float w = (lane < count && T > THRESH) ? T * alpha : 0.0f;

    float cr = r * w, cg = g * w, cb = b * w;

    #pragma unroll
    for (int off = 32; off > 0; off >>= 1) {
        cr += __shfl_down(cr, off, 64);
        cg += __shfl_down(cg, off, 64);
        cb += __shfl_down(cb, off, 64);
        w  += __shfl_down(w,  off, 64);
    }

    if (lane == 0) {
        out[ray * 3 + 0] = cr + bg[0] * (1.0f - w);
        out[ray * 3 + 1] = cg + bg[1] * (1.0f - w);
        out[ray * 3 + 2] = cb + bg[2] * (1.0f - w);
    }
}

extern "C" void kernel_launch(void* const* d_in, const int* in_sizes, int n_in,
                              void* d_out, int out_size, void* d_ws, size_t ws_size,
                              hipStream_t stream) {
    const float* samples  = (const float*)d_in[0];
    const int*   packing  = (const int*)  d_in[1];
    const float* w1       = (const float*)d_in[3];
    const float* b1       = (const float*)d_in[4];
    const float* w2       = (const float*)d_in[5];
    const float* b2       = (const float*)d_in[6];
    const float* w_sigma  = (const float*)d_in[7];
    const float* b_sigma  = (const float*)d_in[8];
    const float* w_rgb1   = (const float*)d_in[9];
    const float* b_rgb1   = (const float*)d_in[10];
    const float* w_rgb2   = (const float*)d_in[11];
    const float* b_rgb2   = (const float*)d_in[12];
    const float* bg       = (const float*)d_in[13];

    float4* smp = (float4*)d_ws;                         // 16 MiB
    uint4*  tbl = (uint4*)((char*)d_ws + TBL_OFF);       // 22.5 KiB frag table
    float*  out = (float*)d_out;

    nerf_build_frags<<<1, 256, 0, stream>>>(
        w1, b1, w2, b2, w_sigma, b_sigma,
        w_rgb1, b_rgb1, w_rgb2, b_rgb2, tbl);

    nerf_mlp_mfma<<<2048, 256, 0, stream>>>(samples, tbl, (float4*)smp);

    nerf_render_kernel<<<(N_RAYS * 64) / 256, 256, 0, stream>>>(smp, packing, bg, out);
}

// Round 10
// 49.255 us; speedup vs baseline: 1.2266x; 1.0019x over previous
//
#include <hip/hip_runtime.h>
#include <hip/hip_bf16.h>
#include <math.h>
#include <stdint.h>

#define N_RAYS    32768
#define N_SAMPLES (N_RAYS * 32)
#define THRESH 0.0001f
#define TBL_OFF  (16u * 1024u * 1024u)   // frag table lives after smp[] in d_ws

typedef __attribute__((ext_vector_type(8))) __bf16 bf16x8;
typedef __attribute__((ext_vector_type(4))) float  f32x4;
typedef float f4a __attribute__((ext_vector_type(4), aligned(4)));

union FragU { __hip_bfloat162 h2[4]; uint32_t w[4]; bf16x8 v; };
union RecU  { bf16x8 v; f32x4 f; uint4 u; };

__device__ inline __hip_bfloat162 pk2(float lo, float hi) {
    float2 t; t.x = lo; t.y = hi;
    return __float22bfloat162_rn(t);
}

__device__ inline bf16x8 pack8(const float* vals) {
    FragU u;
    u.h2[0] = pk2(vals[0], vals[1]);
    u.h2[1] = pk2(vals[2], vals[3]);
    u.h2[2] = pk2(vals[4], vals[5]);
    u.h2[3] = pk2(vals[6], vals[7]);
    return u.v;
}

__device__ inline float rcp_fast(float x) {
    float r;
    asm("v_rcp_f32 %0, %1" : "=v"(r) : "v"(x));
    return r;
}
__device__ inline float sigmoid_fast(float x) { return rcp_fast(1.0f + __expf(-x)); }
__device__ inline float softplus_fast(float x) {
    const float e = __expf(-fabsf(x));
    return fmaxf(x, 0.0f) + __logf(1.0f + e);
}

// ---------------------------------------------------------------------------
// Setup kernel (1 block): build all per-lane weight fragments once into d_ws.
// Frag ids: A1:0-3, A2[t][c]:4+2t+c, Ar1a:8-11, Ar1b:12-15, Ar2:16-17,
//           Ar2f:18, b2i(f32):19-20, arinit(f32):21
// A1 uses B-slots q0..3 (posaug); Ar1b uses B-slots q4..7 (dirsaug) — the two
// input B-fragments are MERGED into one (pos+1 on q0-3, dirs+1 on q4-7, g==0).
// ---------------------------------------------------------------------------
__global__ __launch_bounds__(256) void nerf_build_frags(
    const float* __restrict__ w1,  const float* __restrict__ b1,
    const float* __restrict__ w2,  const float* __restrict__ b2,
    const float* __restrict__ w_sigma, const float* __restrict__ b_sigma,
    const float* __restrict__ w_rgb1,  const float* __restrict__ b_rgb1,
    const float* __restrict__ w_rgb2,  const float* __restrict__ b_rgb2,
    uint4* __restrict__ tbl)
{
    const int wid  = threadIdx.x >> 6;
    const int lane = threadIdx.x & 63;
    const int g    = lane >> 4;
    const int sl   = lane & 15;
    RecU rec;

    if (wid == 0) {
        #pragma unroll
        for (int t = 0; t < 4; ++t) {      // A1 = [w1;b1]^T on q0..3 (g==0)
            float v[8] = {0,0,0,0,0,0,0,0};
            if (g == 0) {
                const int j = t*16 + sl;
                v[0] = w1[j]; v[1] = w1[64+j]; v[2] = w1[128+j]; v[3] = b1[j];
            }
            rec.v = pack8(v); tbl[t*64 + lane] = rec.u;
        }
        #pragma unroll
        for (int t = 0; t < 2; ++t)        // A2 = w2^T, permuted k
            #pragma unroll
            for (int c = 0; c < 2; ++c) {
                float v[8];
                #pragma unroll
                for (int q = 0; q < 8; ++q) {
                    const int j = 16*(2*c + (q>>2)) + 4*g + (q&3);
                    v[q] = w2[j*32 + t*16 + sl];
                }
                rec.v = pack8(v); tbl[(4 + 2*t + c)*64 + lane] = rec.u;
            }
    } else if (wid == 1) {
        #pragma unroll
        for (int t = 0; t < 4; ++t) {      // Ar1a = w_rgb1^T (feats), permuted k
            float v[8];
            #pragma unroll
            for (int q = 0; q < 8; ++q) {
                const int f = 16*(q>>2) + 4*g + (q&3);
                v[q] = w_rgb1[f*64 + t*16 + sl];
            }
            rec.v = pack8(v); tbl[(8 + t)*64 + lane] = rec.u;
        }
        #pragma unroll
        for (int t = 0; t < 4; ++t) {      // Ar1b = dirs rows + b_rgb1 on q4..7 (g==0)
            float v[8] = {0,0,0,0,0,0,0,0};
            if (g == 0) {
                const int j = t*16 + sl;
                v[4] = w_rgb1[32*64 + j]; v[5] = w_rgb1[33*64 + j];
                v[6] = w_rgb1[34*64 + j]; v[7] = b_rgb1[j];
            }
            rec.v = pack8(v); tbl[(12 + t)*64 + lane] = rec.u;
        }
    } else if (wid == 2) {
        #pragma unroll
        for (int c = 0; c < 2; ++c) {      // Ar2 = w_rgb2^T rows 0..2, permuted k
            float v[8];
            #pragma unroll
            for (int q = 0; q < 8; ++q) {
                const int hh = 16*(2*c + (q>>2)) + 4*g + (q&3);
                v[q] = (sl < 3) ? w_rgb2[hh*3 + sl] : 0.0f;
            }
            rec.v = pack8(v); tbl[(16 + c)*64 + lane] = rec.u;
        }
        {                                  // Ar2f = w_sigma on row m=3
            float v[8];
            #pragma unroll
            for (int q = 0; q < 8; ++q) {
                const int f = 16*(q>>2) + 4*g + (q&3);
                v[q] = (sl == 3) ? w_sigma[f] : 0.0f;
            }
            rec.v = pack8(v); tbl[18*64 + lane] = rec.u;
        }
        #pragma unroll
        for (int t = 0; t < 2; ++t) {      // b2i (f32x4, C-operand layout m=4g+r)
            #pragma unroll
            for (int r = 0; r < 4; ++r) rec.f[r] = b2[16*t + 4*g + r];
            tbl[(19 + t)*64 + lane] = rec.u;
        }
        {                                  // arinit (f32x4, uniform)
            rec.f[0] = b_rgb2[0]; rec.f[1] = b_rgb2[1];
            rec.f[2] = b_rgb2[2]; rec.f[3] = b_sigma[0];
            tbl[21*64 + lane] = rec.u;
        }
    }
}

// ---------------------------------------------------------------------------
// Main MFMA MLP. One wave = 128 contiguous samples (4 pairs, dual-stream),
// sample staging double-buffered (2-deep) to fit the 3-waves/SIMD register
// budget (512/3 = 170): frags ~88 (AGPR-able) + stage 32 + accs ~32 + misc.
// D layout: n=lane&15, m=4*(lane>>4)+reg; B k-map == previous D layout.
// ---------------------------------------------------------------------------
__global__ __launch_bounds__(256, 3) void nerf_mlp_mfma(
    const float* __restrict__ samples,   // (N_SAMPLES, 7)
    const uint4* __restrict__ tbl,       // [22][64] frag table
    float4* __restrict__ out)            // (N_SAMPLES): tau, r, g, b
{
    const int lane = threadIdx.x & 63;
    const int g    = lane >> 4;
    const int sl   = lane & 15;
    const int wgid = (blockIdx.x * blockDim.x + threadIdx.x) >> 6;
    const int base0 = wgid * 128;

    // ---- pair-0 sample loads issued first (2-deep rotating buffers)
    f4a sa[2][2], sb[2][2];
    {
        const float* sp0 = samples + (size_t)(base0 + sl) * 7;
        const float* sp1 = samples + (size_t)(base0 + 16 + sl) * 7;
        sa[0][0] = *(const f4a*)sp0;  sb[0][0] = *(const f4a*)(sp0 + 3);
        sa[0][1] = *(const f4a*)sp1;  sb[0][1] = *(const f4a*)(sp1 + 3);
    }

    // ---- coalesced fragment loads (L2-resident table)
    bf16x8 A1[4], A2[2][2], Ar1a[4], Ar1b[4], Ar2[2], Ar2f;
    f32x4 b2i[2], arinit;
    {
        RecU r_;
        #pragma unroll
        for (int t = 0; t < 4; ++t) { r_.u = tbl[t*64 + lane];       A1[t]   = r_.v; }
        #pragma unroll
        for (int t = 0; t < 2; ++t)
            #pragma unroll
            for (int c = 0; c < 2; ++c) { r_.u = tbl[(4+2*t+c)*64 + lane]; A2[t][c] = r_.v; }
        #pragma unroll
        for (int t = 0; t < 4; ++t) { r_.u = tbl[(8+t)*64 + lane];   Ar1a[t] = r_.v; }
        #pragma unroll
        for (int t = 0; t < 4; ++t) { r_.u = tbl[(12+t)*64 + lane];  Ar1b[t] = r_.v; }
        #pragma unroll
        for (int c = 0; c < 2; ++c) { r_.u = tbl[(16+c)*64 + lane];  Ar2[c]  = r_.v; }
        r_.u = tbl[18*64 + lane]; Ar2f = r_.v;
        r_.u = tbl[19*64 + lane]; b2i[0] = r_.f;
        r_.u = tbl[20*64 + lane]; b2i[1] = r_.f;
        r_.u = tbl[21*64 + lane]; arinit = r_.f;
    }

    const float biasone = (g == 0) ? 1.0f : 0.0f;
    const f32x4 zero4 = {0.f, 0.f, 0.f, 0.f};

    #pragma unroll
    for (int it = 0; it < 4; ++it) {
        const int cb = it & 1;           // current buffer (static after unroll)
        const int nb = (it + 1) & 1;     // next buffer
        if (it < 3) {                    // prefetch next pair into other buffer
            const int nbase = base0 + (it + 1) * 32;
            const float* sp0 = samples + (size_t)(nbase + sl) * 7;
            const float* sp1 = samples + (size_t)(nbase + 16 + sl) * 7;
            sa[nb][0] = *(const f4a*)sp0;  sb[nb][0] = *(const f4a*)(sp0 + 3);
            sa[nb][1] = *(const f4a*)sp1;  sb[nb][1] = *(const f4a*)(sp1 + 3);
        }

        // ---- merged input fragment: pos+1 on q0-3, dirs+1 on q4-7 (g==0 slots)
        FragU bin[2];
        #pragma unroll
        for (int s = 0; s < 2; ++s) {
            bin[s].h2[0] = pk2(sa[cb][s].x, sa[cb][s].y);
            bin[s].h2[1] = pk2(sa[cb][s].z, biasone);
            bin[s].h2[2] = pk2(sb[cb][s].x, sb[cb][s].y);
            bin[s].h2[3] = pk2(sb[cb][s].z, biasone);
        }

        // layer1 (A1 zero on q4-7, so dirs slots are ignored)
        f32x4 accL1[2][4];
        #pragma unroll
        for (int t = 0; t < 4; ++t)
            #pragma unroll
            for (int s = 0; s < 2; ++s)
                accL1[s][t] = __builtin_amdgcn_mfma_f32_16x16x32_bf16(A1[t], bin[s].v, zero4, 0,0,0);

        FragU B2c[2][2];
        #pragma unroll
        for (int s = 0; s < 2; ++s)
            #pragma unroll
            for (int c = 0; c < 2; ++c) {
                B2c[s][c].h2[0] = pk2(fmaxf(accL1[s][2*c  ][0],0.f), fmaxf(accL1[s][2*c  ][1],0.f));
                B2c[s][c].h2[1] = pk2(fmaxf(accL1[s][2*c  ][2],0.f), fmaxf(accL1[s][2*c  ][3],0.f));
                B2c[s][c].h2[2] = pk2(fmaxf(accL1[s][2*c+1][0],0.f), fmaxf(accL1[s][2*c+1][1],0.f));
                B2c[s][c].h2[3] = pk2(fmaxf(accL1[s][2*c+1][2],0.f), fmaxf(accL1[s][2*c+1][3],0.f));
            }

        // layer2 (+b2 via C)
        f32x4 accL2[2][2];
        #pragma unroll
        for (int t = 0; t < 2; ++t)
            #pragma unroll
            for (int s = 0; s < 2; ++s) {
                accL2[s][t] = __builtin_amdgcn_mfma_f32_16x16x32_bf16(A2[t][0], B2c[s][0].v, b2i[t], 0,0,0);
                accL2[s][t] = __builtin_amdgcn_mfma_f32_16x16x32_bf16(A2[t][1], B2c[s][1].v, accL2[s][t], 0,0,0);
            }
        FragU Bf[2];
        #pragma unroll
        for (int s = 0; s < 2; ++s) {
            Bf[s].h2[0] = pk2(accL2[s][0][0], accL2[s][0][1]);
            Bf[s].h2[1] = pk2(accL2[s][0][2], accL2[s][0][3]);
            Bf[s].h2[2] = pk2(accL2[s][1][0], accL2[s][1][1]);
            Bf[s].h2[3] = pk2(accL2[s][1][2], accL2[s][1][3]);
        }

        // rgb1: h = relu(Ar1a.feats + Ar1b.[dirs;1])  (Ar1b zero on q0-3)
        f32x4 ah[2][4];
        #pragma unroll
        for (int t = 0; t < 4; ++t)
            #pragma unroll
            for (int s = 0; s < 2; ++s) {
                ah[s][t] = __builtin_amdgcn_mfma_f32_16x16x32_bf16(Ar1a[t], Bf[s].v, zero4, 0,0,0);
                ah[s][t] = __builtin_amdgcn_mfma_f32_16x16x32_bf16(Ar1b[t], bin[s].v, ah[s][t], 0,0,0);
            }
        FragU Bh[2][2];
        #pragma unroll
        for (int s = 0; s < 2; ++s)
            #pragma unroll
            for (int c = 0; c < 2; ++c) {
                Bh[s][c].h2[0] = pk2(fmaxf(ah[s][2*c  ][0],0.f), fmaxf(ah[s][2*c  ][1],0.f));
                Bh[s][c].h2[1] = pk2(fmaxf(ah[s][2*c  ][2],0.f), fmaxf(ah[s][2*c  ][3],0.f));
                Bh[s][c].h2[2] = pk2(fmaxf(ah[s][2*c+1][0],0.f), fmaxf(ah[s][2*c+1][1],0.f));
                Bh[s][c].h2[3] = pk2(fmaxf(ah[s][2*c+1][2],0.f), fmaxf(ah[s][2*c+1][3],0.f));
            }

        // rgb2 (+sigma m=3)
        f32x4 ar[2];
        #pragma unroll
        for (int s = 0; s < 2; ++s) {
            ar[s] = __builtin_amdgcn_mfma_f32_16x16x32_bf16(Ar2[0], Bh[s][0].v, arinit, 0,0,0);
            ar[s] = __builtin_amdgcn_mfma_f32_16x16x32_bf16(Ar2[1], Bh[s][1].v, ar[s], 0,0,0);
            ar[s] = __builtin_amdgcn_mfma_f32_16x16x32_bf16(Ar2f,   Bf[s].v,    ar[s], 0,0,0);
        }

        #pragma unroll
        for (int s = 0; s < 2; ++s) {
            const float rr    = sigmoid_fast(ar[s][0]);
            const float gg    = sigmoid_fast(ar[s][1]);
            const float bb    = sigmoid_fast(ar[s][2]);
            const float sigma = softplus_fast(ar[s][3]);
            const float tau   = sigma * sb[cb][s].w;
            if (g == 0) out[base0 + it * 32 + s * 16 + sl] = make_float4(tau, rr, gg, bb);
        }
    }
}

// ---------------------------------------------------------------------------
// Kernel 2: one wave per ray — scan tau, gate, reduce.
// ---------------------------------------------------------------------------
__global__ __launch_bounds__(256) void nerf_render_kernel(
    const float4* __restrict__ smp,
    const int*    __restrict__ packing,
    const float*  __restrict__ bg,
    float*        __restrict__ out)
{
    const int gtid = blockIdx.x * blockDim.x + threadIdx.x;
    const int ray  = gtid >> 6;
    const int lane = threadIdx.x & 63;
    if (ray >= N_RAYS) return;

    const int start = packing[2 * ray];
    const int count = packing[2 * ray + 1];

    float tau = 0.0f, r = 0.0f, g = 0.0f, b = 0.0f;
    if (lane < count) {
        const float4 v = smp[start + lane];
        tau = v.x; r = v.y; g = v.z; b = v.w;
    }

    float incl = tau;
    #pragma unroll
    for (int off = 1; off < 64; off <<= 1) {
        const float v = __shfl_up(incl, off, 64);
        if (lane >= off) incl += v;
    }
    const float c_excl = incl - tau;

    const float T     = __expf(-c_excl);
    const float alpha = 1.0f - __expf(-tau);
    float w = (lane < count && T > THRESH) ? T * alpha : 0.0f;

    float cr = r * w, cg = g * w, cb = b * w;

    #pragma unroll
    for (int off = 32; off > 0; off >>= 1) {
        cr += __shfl_down(cr, off, 64);
        cg += __shfl_down(cg, off, 64);
        cb += __shfl_down(cb, off, 64);
        w  += __shfl_down(w,  off, 64);
    }

    if (lane == 0) {
        out[ray * 3 + 0] = cr + bg[0] * (1.0f - w);
        out[ray * 3 + 1] = cg + bg[1] * (1.0f - w);
        out[ray * 3 + 2] = cb + bg[2] * (1.0f - w);
    }
}

extern "C" void kernel_launch(void* const* d_in, const int* in_sizes, int n_in,
                              void* d_out, int out_size, void* d_ws, size_t ws_size,
                              hipStream_t stream) {
    const float* samples  = (const float*)d_in[0];
    const int*   packing  = (const int*)  d_in[1];
    const float* w1       = (const float*)d_in[3];
    const float* b1       = (const float*)d_in[4];
    const float* w2       = (const float*)d_in[5];
    const float* b2       = (const float*)d_in[6];
    const float* w_sigma  = (const float*)d_in[7];
    const float* b_sigma  = (const float*)d_in[8];
    const float* w_rgb1   = (const float*)d_in[9];
    const float* b_rgb1   = (const float*)d_in[10];
    const float* w_rgb2   = (const float*)d_in[11];
    const float* b_rgb2   = (const float*)d_in[12];
    const float* bg       = (const float*)d_in[13];

    float4* smp = (float4*)d_ws;                         // 16 MiB
    uint4*  tbl = (uint4*)((char*)d_ws + TBL_OFF);       // 22.5 KiB frag table
    float*  out = (float*)d_out;

    nerf_build_frags<<<1, 256, 0, stream>>>(
        w1, b1, w2, b2, w_sigma, b_sigma,
        w_rgb1, b_rgb1, w_rgb2, b_rgb2, tbl);

    nerf_mlp_mfma<<<2048, 256, 0, stream>>>(samples, tbl, (float4*)smp);

    nerf_render_kernel<<<(N_RAYS * 64) / 256, 256, 0, stream>>>(smp, packing, bg, out);
}

// Round 11
// 48.735 us; speedup vs baseline: 1.2397x; 1.0107x over previous
//
#include <hip/hip_runtime.h>
#include <hip/hip_bf16.h>
#include <math.h>
#include <stdint.h>

#define N_RAYS    32768
#define N_SAMPLES (N_RAYS * 32)
#define THRESH 0.0001f
#define TBL_OFF  (16u * 1024u * 1024u)   // frag table lives after smp[] in d_ws

typedef __attribute__((ext_vector_type(8))) __bf16 bf16x8;
typedef __attribute__((ext_vector_type(4))) float  f32x4;
typedef float f4a __attribute__((ext_vector_type(4), aligned(4)));

union FragU { __hip_bfloat162 h2[4]; uint32_t w[4]; bf16x8 v; };
union RecU  { bf16x8 v; f32x4 f; uint4 u; };

__device__ inline __hip_bfloat162 pk2(float lo, float hi) {
    float2 t; t.x = lo; t.y = hi;
    return __float22bfloat162_rn(t);
}

__device__ inline bf16x8 pack8(const float* vals) {
    FragU u;
    u.h2[0] = pk2(vals[0], vals[1]);
    u.h2[1] = pk2(vals[2], vals[3]);
    u.h2[2] = pk2(vals[4], vals[5]);
    u.h2[3] = pk2(vals[6], vals[7]);
    return u.v;
}

__device__ inline float rcp_fast(float x) {
    float r;
    asm("v_rcp_f32 %0, %1" : "=v"(r) : "v"(x));
    return r;
}
__device__ inline float sigmoid_fast(float x) { return rcp_fast(1.0f + __expf(-x)); }
__device__ inline float softplus_fast(float x) {
    const float e = __expf(-fabsf(x));
    return fmaxf(x, 0.0f) + __logf(1.0f + e);
}

// ---------------------------------------------------------------------------
// Setup kernel (1 block): build all per-lane weight fragments once into d_ws.
// Frag ids: A1:0-3, A2[t][c]:4+2t+c, Ar1a:8-11, Ar1b:12-15, Ar2:16-17,
//           Ar2f:18, b2i(f32):19-20, arinit(f32):21
// A1 uses B-slots q0..3 (posaug); Ar1b uses B-slots q4..7 (dirsaug): one
// merged input fragment (pos+1 on q0-3, dirs+1 on q4-7, g==0 slots).
// ---------------------------------------------------------------------------
__global__ __launch_bounds__(256) void nerf_build_frags(
    const float* __restrict__ w1,  const float* __restrict__ b1,
    const float* __restrict__ w2,  const float* __restrict__ b2,
    const float* __restrict__ w_sigma, const float* __restrict__ b_sigma,
    const float* __restrict__ w_rgb1,  const float* __restrict__ b_rgb1,
    const float* __restrict__ w_rgb2,  const float* __restrict__ b_rgb2,
    uint4* __restrict__ tbl)
{
    const int wid  = threadIdx.x >> 6;
    const int lane = threadIdx.x & 63;
    const int g    = lane >> 4;
    const int sl   = lane & 15;
    RecU rec;

    if (wid == 0) {
        #pragma unroll
        for (int t = 0; t < 4; ++t) {      // A1 = [w1;b1]^T on q0..3 (g==0)
            float v[8] = {0,0,0,0,0,0,0,0};
            if (g == 0) {
                const int j = t*16 + sl;
                v[0] = w1[j]; v[1] = w1[64+j]; v[2] = w1[128+j]; v[3] = b1[j];
            }
            rec.v = pack8(v); tbl[t*64 + lane] = rec.u;
        }
        #pragma unroll
        for (int t = 0; t < 2; ++t)        // A2 = w2^T, permuted k
            #pragma unroll
            for (int c = 0; c < 2; ++c) {
                float v[8];
                #pragma unroll
                for (int q = 0; q < 8; ++q) {
                    const int j = 16*(2*c + (q>>2)) + 4*g + (q&3);
                    v[q] = w2[j*32 + t*16 + sl];
                }
                rec.v = pack8(v); tbl[(4 + 2*t + c)*64 + lane] = rec.u;
            }
    } else if (wid == 1) {
        #pragma unroll
        for (int t = 0; t < 4; ++t) {      // Ar1a = w_rgb1^T (feats), permuted k
            float v[8];
            #pragma unroll
            for (int q = 0; q < 8; ++q) {
                const int f = 16*(q>>2) + 4*g + (q&3);
                v[q] = w_rgb1[f*64 + t*16 + sl];
            }
            rec.v = pack8(v); tbl[(8 + t)*64 + lane] = rec.u;
        }
        #pragma unroll
        for (int t = 0; t < 4; ++t) {      // Ar1b = dirs rows + b_rgb1 on q4..7 (g==0)
            float v[8] = {0,0,0,0,0,0,0,0};
            if (g == 0) {
                const int j = t*16 + sl;
                v[4] = w_rgb1[32*64 + j]; v[5] = w_rgb1[33*64 + j];
                v[6] = w_rgb1[34*64 + j]; v[7] = b_rgb1[j];
            }
            rec.v = pack8(v); tbl[(12 + t)*64 + lane] = rec.u;
        }
    } else if (wid == 2) {
        #pragma unroll
        for (int c = 0; c < 2; ++c) {      // Ar2 = w_rgb2^T rows 0..2, permuted k
            float v[8];
            #pragma unroll
            for (int q = 0; q < 8; ++q) {
                const int hh = 16*(2*c + (q>>2)) + 4*g + (q&3);
                v[q] = (sl < 3) ? w_rgb2[hh*3 + sl] : 0.0f;
            }
            rec.v = pack8(v); tbl[(16 + c)*64 + lane] = rec.u;
        }
        {                                  // Ar2f = w_sigma on row m=3
            float v[8];
            #pragma unroll
            for (int q = 0; q < 8; ++q) {
                const int f = 16*(q>>2) + 4*g + (q&3);
                v[q] = (sl == 3) ? w_sigma[f] : 0.0f;
            }
            rec.v = pack8(v); tbl[18*64 + lane] = rec.u;
        }
        #pragma unroll
        for (int t = 0; t < 2; ++t) {      // b2i (f32x4, C-operand layout m=4g+r)
            #pragma unroll
            for (int r = 0; r < 4; ++r) rec.f[r] = b2[16*t + 4*g + r];
            tbl[(19 + t)*64 + lane] = rec.u;
        }
        {                                  // arinit (f32x4, uniform)
            rec.f[0] = b_rgb2[0]; rec.f[1] = b_rgb2[1];
            rec.f[2] = b_rgb2[2]; rec.f[3] = b_sigma[0];
            tbl[21*64 + lane] = rec.u;
        }
    }
}

// ---------------------------------------------------------------------------
// Main MFMA MLP. SINGLE-STREAM: one wave = 8 sequential 16-sample tiles,
// 2-deep sample prefetch. Dropping the dual-stream halves accumulator
// pressure (unified regs ~130-145 < 170) -> 3+ waves/SIMD resident; wave-level
// TLP replaces intra-wave ILP.
// D layout: n=lane&15, m=4*(lane>>4)+reg; B k-map == previous D layout.
// ---------------------------------------------------------------------------
__global__ __launch_bounds__(256, 3) void nerf_mlp_mfma(
    const float* __restrict__ samples,   // (N_SAMPLES, 7)
    const uint4* __restrict__ tbl,       // [22][64] frag table
    float4* __restrict__ out)            // (N_SAMPLES): tau, r, g, b
{
    const int lane = threadIdx.x & 63;
    const int g    = lane >> 4;
    const int sl   = lane & 15;
    const int wgid = (blockIdx.x * blockDim.x + threadIdx.x) >> 6;
    const int base0 = wgid * 128;        // 8 tiles x 16 samples

    // ---- tile-0 sample loads issued first (2-deep rotating buffers)
    f4a sa[2], sb[2];
    {
        const float* sp = samples + (size_t)(base0 + sl) * 7;
        sa[0] = *(const f4a*)sp;  sb[0] = *(const f4a*)(sp + 3);
    }

    // ---- coalesced fragment loads (L2-resident table)
    bf16x8 A1[4], A2[2][2], Ar1a[4], Ar1b[4], Ar2[2], Ar2f;
    f32x4 b2i[2], arinit;
    {
        RecU r_;
        #pragma unroll
        for (int t = 0; t < 4; ++t) { r_.u = tbl[t*64 + lane];       A1[t]   = r_.v; }
        #pragma unroll
        for (int t = 0; t < 2; ++t)
            #pragma unroll
            for (int c = 0; c < 2; ++c) { r_.u = tbl[(4+2*t+c)*64 + lane]; A2[t][c] = r_.v; }
        #pragma unroll
        for (int t = 0; t < 4; ++t) { r_.u = tbl[(8+t)*64 + lane];   Ar1a[t] = r_.v; }
        #pragma unroll
        for (int t = 0; t < 4; ++t) { r_.u = tbl[(12+t)*64 + lane];  Ar1b[t] = r_.v; }
        #pragma unroll
        for (int c = 0; c < 2; ++c) { r_.u = tbl[(16+c)*64 + lane];  Ar2[c]  = r_.v; }
        r_.u = tbl[18*64 + lane]; Ar2f = r_.v;
        r_.u = tbl[19*64 + lane]; b2i[0] = r_.f;
        r_.u = tbl[20*64 + lane]; b2i[1] = r_.f;
        r_.u = tbl[21*64 + lane]; arinit = r_.f;
    }

    const float biasone = (g == 0) ? 1.0f : 0.0f;
    const f32x4 zero4 = {0.f, 0.f, 0.f, 0.f};

    #pragma unroll
    for (int it = 0; it < 8; ++it) {
        const int cb = it & 1;           // static after unroll
        const int nb = (it + 1) & 1;
        if (it < 7) {                    // prefetch next tile into other buffer
            const float* sp = samples + (size_t)(base0 + (it + 1) * 16 + sl) * 7;
            sa[nb] = *(const f4a*)sp;  sb[nb] = *(const f4a*)(sp + 3);
        }

        // merged input fragment: pos+1 on q0-3, dirs+1 on q4-7 (g==0 slots)
        FragU bin;
        bin.h2[0] = pk2(sa[cb].x, sa[cb].y);
        bin.h2[1] = pk2(sa[cb].z, biasone);
        bin.h2[2] = pk2(sb[cb].x, sb[cb].y);
        bin.h2[3] = pk2(sb[cb].z, biasone);

        // layer1 (A1 zero on q4-7 -> dirs slots ignored)
        f32x4 accL1[4];
        #pragma unroll
        for (int t = 0; t < 4; ++t)
            accL1[t] = __builtin_amdgcn_mfma_f32_16x16x32_bf16(A1[t], bin.v, zero4, 0,0,0);

        FragU B2c[2];
        #pragma unroll
        for (int c = 0; c < 2; ++c) {
            B2c[c].h2[0] = pk2(fmaxf(accL1[2*c  ][0],0.f), fmaxf(accL1[2*c  ][1],0.f));
            B2c[c].h2[1] = pk2(fmaxf(accL1[2*c  ][2],0.f), fmaxf(accL1[2*c  ][3],0.f));
            B2c[c].h2[2] = pk2(fmaxf(accL1[2*c+1][0],0.f), fmaxf(accL1[2*c+1][1],0.f));
            B2c[c].h2[3] = pk2(fmaxf(accL1[2*c+1][2],0.f), fmaxf(accL1[2*c+1][3],0.f));
        }

        // layer2 (+b2 via C)
        f32x4 accL2[2];
        #pragma unroll
        for (int t = 0; t < 2; ++t) {
            accL2[t] = __builtin_amdgcn_mfma_f32_16x16x32_bf16(A2[t][0], B2c[0].v, b2i[t], 0,0,0);
            accL2[t] = __builtin_amdgcn_mfma_f32_16x16x32_bf16(A2[t][1], B2c[1].v, accL2[t], 0,0,0);
        }
        FragU Bf;
        Bf.h2[0] = pk2(accL2[0][0], accL2[0][1]);
        Bf.h2[1] = pk2(accL2[0][2], accL2[0][3]);
        Bf.h2[2] = pk2(accL2[1][0], accL2[1][1]);
        Bf.h2[3] = pk2(accL2[1][2], accL2[1][3]);

        // rgb1: h = relu(Ar1a.feats + Ar1b.[dirs;1])  (Ar1b zero on q0-3)
        f32x4 ah[4];
        #pragma unroll
        for (int t = 0; t < 4; ++t) {
            ah[t] = __builtin_amdgcn_mfma_f32_16x16x32_bf16(Ar1a[t], Bf.v, zero4, 0,0,0);
            ah[t] = __builtin_amdgcn_mfma_f32_16x16x32_bf16(Ar1b[t], bin.v, ah[t], 0,0,0);
        }
        FragU Bh[2];
        #pragma unroll
        for (int c = 0; c < 2; ++c) {
            Bh[c].h2[0] = pk2(fmaxf(ah[2*c  ][0],0.f), fmaxf(ah[2*c  ][1],0.f));
            Bh[c].h2[1] = pk2(fmaxf(ah[2*c  ][2],0.f), fmaxf(ah[2*c  ][3],0.f));
            Bh[c].h2[2] = pk2(fmaxf(ah[2*c+1][0],0.f), fmaxf(ah[2*c+1][1],0.f));
            Bh[c].h2[3] = pk2(fmaxf(ah[2*c+1][2],0.f), fmaxf(ah[2*c+1][3],0.f));
        }

        // rgb2 (+sigma m=3), biases via C-init
        f32x4 ar;
        ar = __builtin_amdgcn_mfma_f32_16x16x32_bf16(Ar2[0], Bh[0].v, arinit, 0,0,0);
        ar = __builtin_amdgcn_mfma_f32_16x16x32_bf16(Ar2[1], Bh[1].v, ar, 0,0,0);
        ar = __builtin_amdgcn_mfma_f32_16x16x32_bf16(Ar2f,   Bf.v,    ar, 0,0,0);

        const float rr    = sigmoid_fast(ar[0]);
        const float gg    = sigmoid_fast(ar[1]);
        const float bb    = sigmoid_fast(ar[2]);
        const float sigma = softplus_fast(ar[3]);
        const float tau   = sigma * sb[cb].w;
        if (g == 0) out[base0 + it * 16 + sl] = make_float4(tau, rr, gg, bb);
    }
}

// ---------------------------------------------------------------------------
// Kernel 2: one wave per ray — scan tau, gate, reduce.
// ---------------------------------------------------------------------------
__global__ __launch_bounds__(256) void nerf_render_kernel(
    const float4* __restrict__ smp,
    const int*    __restrict__ packing,
    const float*  __restrict__ bg,
    float*        __restrict__ out)
{
    const int gtid = blockIdx.x * blockDim.x + threadIdx.x;
    const int ray  = gtid >> 6;
    const int lane = threadIdx.x & 63;
    if (ray >= N_RAYS) return;

    const int start = packing[2 * ray];
    const int count = packing[2 * ray + 1];

    float tau = 0.0f, r = 0.0f, g = 0.0f, b = 0.0f;
    if (lane < count) {
        const float4 v = smp[start + lane];
        tau = v.x; r = v.y; g = v.z; b = v.w;
    }

    float incl = tau;
    #pragma unroll
    for (int off = 1; off < 64; off <<= 1) {
        const float v = __shfl_up(incl, off, 64);
        if (lane >= off) incl += v;
    }
    const float c_excl = incl - tau;

    const float T     = __expf(-c_excl);
    const float alpha = 1.0f - __expf(-tau);
    float w = (lane < count && T > THRESH) ? T * alpha : 0.0f;

    float cr = r * w, cg = g * w, cb = b * w;

    #pragma unroll
    for (int off = 32; off > 0; off >>= 1) {
        cr += __shfl_down(cr, off, 64);
        cg += __shfl_down(cg, off, 64);
        cb += __shfl_down(cb, off, 64);
        w  += __shfl_down(w,  off, 64);
    }

    if (lane == 0) {
        out[ray * 3 + 0] = cr + bg[0] * (1.0f - w);
        out[ray * 3 + 1] = cg + bg[1] * (1.0f - w);
        out[ray * 3 + 2] = cb + bg[2] * (1.0f - w);
    }
}

extern "C" void kernel_launch(void* const* d_in, const int* in_sizes, int n_in,
                              void* d_out, int out_size, void* d_ws, size_t ws_size,
                              hipStream_t stream) {
    const float* samples  = (const float*)d_in[0];
    const int*   packing  = (const int*)  d_in[1];
    const float* w1       = (const float*)d_in[3];
    const float* b1       = (const float*)d_in[4];
    const float* w2       = (const float*)d_in[5];
    const float* b2       = (const float*)d_in[6];
    const float* w_sigma  = (const float*)d_in[7];
    const float* b_sigma  = (const float*)d_in[8];
    const float* w_rgb1   = (const float*)d_in[9];
    const float* b_rgb1   = (const float*)d_in[10];
    const float* w_rgb2   = (const float*)d_in[11];
    const float* b_rgb2   = (const float*)d_in[12];
    const float* bg       = (const float*)d_in[13];

    float4* smp = (float4*)d_ws;                         // 16 MiB
    uint4*  tbl = (uint4*)((char*)d_ws + TBL_OFF);       // 22.5 KiB frag table
    float*  out = (float*)d_out;

    nerf_build_frags<<<1, 256, 0, stream>>>(
        w1, b1, w2, b2, w_sigma, b_sigma,
        w_rgb1, b_rgb1, w_rgb2, b_rgb2, tbl);

    nerf_mlp_mfma<<<2048, 256, 0, stream>>>(samples, tbl, (float4*)smp);

    nerf_render_kernel<<<(N_RAYS * 64) / 256, 256, 0, stream>>>(smp, packing, bg, out);
}

// Round 12
// 47.539 us; speedup vs baseline: 1.2709x; 1.0252x over previous
//
#include <hip/hip_runtime.h>
#include <hip/hip_bf16.h>
#include <math.h>
#include <stdint.h>

#define N_RAYS    32768
#define N_SAMPLES (N_RAYS * 32)
#define THRESH 0.0001f
#define TBL_OFF  (16u * 1024u * 1024u)   // frag table after smp[] in d_ws

// record ids in frag table (one uint4 per lane per record)
#define R_A1   0   // +t (2)
#define R_A2   2   // +c (4)
#define R_R1A  6   // +2t+c (4)
#define R_R1B  10  // +t (2)
#define R_AR2  12  // +c (4)
#define R_AR2F 16  // +c (2)
#define R_B2I  18  // +i (4)
#define R_ARI  22  // +i (4)   -> 26 records total

typedef __attribute__((ext_vector_type(8)))  __bf16 bf16x8;
typedef __attribute__((ext_vector_type(16))) float  f32x16;
typedef float f4a __attribute__((ext_vector_type(4), aligned(4)));

union FragU  { __hip_bfloat162 h2[4]; uint32_t w[4]; bf16x8 v; };
union RecU   { bf16x8 v; uint4 u; };
union Rec16U { f32x16 v; uint4 u[4]; float f[16]; };

__device__ inline __hip_bfloat162 pk2(float lo, float hi) {
    float2 t; t.x = lo; t.y = hi;
    return __float22bfloat162_rn(t);
}

__device__ inline bf16x8 pack8(const float* vals) {
    FragU u;
    u.h2[0] = pk2(vals[0], vals[1]);
    u.h2[1] = pk2(vals[2], vals[3]);
    u.h2[2] = pk2(vals[4], vals[5]);
    u.h2[3] = pk2(vals[6], vals[7]);
    return u.v;
}

__device__ inline float rcp_fast(float x) {
    float r;
    asm("v_rcp_f32 %0, %1" : "=v"(r) : "v"(x));
    return r;
}
__device__ inline float sigmoid_fast(float x) { return rcp_fast(1.0f + __expf(-x)); }
__device__ inline float softplus_fast(float x) {
    const float e = __expf(-fabsf(x));
    return fmaxf(x, 0.0f) + __logf(1.0f + e);
}

// B-fragment from accumulator: element q = acc[P + q], optionally relu'd.
template <int P>
__device__ inline bf16x8 packB_relu(f32x16 a) {
    FragU u;
    u.h2[0] = pk2(fmaxf(a[P+0],0.f), fmaxf(a[P+1],0.f));
    u.h2[1] = pk2(fmaxf(a[P+2],0.f), fmaxf(a[P+3],0.f));
    u.h2[2] = pk2(fmaxf(a[P+4],0.f), fmaxf(a[P+5],0.f));
    u.h2[3] = pk2(fmaxf(a[P+6],0.f), fmaxf(a[P+7],0.f));
    return u.v;
}
template <int P>
__device__ inline bf16x8 packB_plain(f32x16 a) {
    FragU u;
    u.h2[0] = pk2(a[P+0], a[P+1]);
    u.h2[1] = pk2(a[P+2], a[P+3]);
    u.h2[2] = pk2(a[P+4], a[P+5]);
    u.h2[3] = pk2(a[P+6], a[P+7]);
    return u.v;
}

// ---------------------------------------------------------------------------
// Setup kernel: build per-lane weight fragments for the 32x32x16 path.
// Conventions (self-consistent A/B k-slot permutation; D layout HW-verified:
// col=lane&31, row=(reg&3)+8*(reg>>2)+4*(lane>>5)):
//   rr(q,h) = (q&3) + 8*(q>>2) + 4*h
//   layer-K ksteps c: slot (h,q) <-> index 16c + rr(q,h)
//   input kstep: h=0 slots q0..3 = pos,1 ; h=1 slots q0..3 = dirs,1
// ---------------------------------------------------------------------------
__global__ __launch_bounds__(256) void nerf_build_frags(
    const float* __restrict__ w1,  const float* __restrict__ b1,
    const float* __restrict__ w2,  const float* __restrict__ b2,
    const float* __restrict__ w_sigma, const float* __restrict__ b_sigma,
    const float* __restrict__ w_rgb1,  const float* __restrict__ b_rgb1,
    const float* __restrict__ w_rgb2,  const float* __restrict__ b_rgb2,
    uint4* __restrict__ tbl)
{
    const int wid  = threadIdx.x >> 6;
    const int lane = threadIdx.x & 63;
    const int m    = lane & 31;          // A-operand row (tile-local)
    const int h    = lane >> 5;
    RecU rec;

    if (wid == 0) {
        #pragma unroll
        for (int t = 0; t < 2; ++t) {        // A1: rows j=32t+m; k slots h=0,q0..3
            float v[8] = {0,0,0,0,0,0,0,0};
            if (h == 0) {
                const int j = 32*t + m;
                v[0] = w1[j]; v[1] = w1[64+j]; v[2] = w1[128+j]; v[3] = b1[j];
            }
            rec.v = pack8(v); tbl[(R_A1+t)*64 + lane] = rec.u;
        }
        #pragma unroll
        for (int c = 0; c < 4; ++c) {        // A2: A[f=m][j=16c+rr(q,h)] = w2[j*32+f]
            float v[8];
            #pragma unroll
            for (int q = 0; q < 8; ++q) {
                const int j = 16*c + (q&3) + 8*(q>>2) + 4*h;
                v[q] = w2[j*32 + m];
            }
            rec.v = pack8(v); tbl[(R_A2+c)*64 + lane] = rec.u;
        }
    } else if (wid == 1) {
        #pragma unroll
        for (int t = 0; t < 2; ++t)          // Ar1a: rows j=32t+m; k=f=16c+rr
            #pragma unroll
            for (int c = 0; c < 2; ++c) {
                float v[8];
                #pragma unroll
                for (int q = 0; q < 8; ++q) {
                    const int f = 16*c + (q&3) + 8*(q>>2) + 4*h;
                    v[q] = w_rgb1[f*64 + 32*t + m];
                }
                rec.v = pack8(v); tbl[(R_R1A+2*t+c)*64 + lane] = rec.u;
            }
        #pragma unroll
        for (int t = 0; t < 2; ++t) {        // Ar1b: dirs+bias on h=1 slots q0..3
            float v[8] = {0,0,0,0,0,0,0,0};
            if (h == 1) {
                const int j = 32*t + m;
                v[0] = w_rgb1[32*64 + j]; v[1] = w_rgb1[33*64 + j];
                v[2] = w_rgb1[34*64 + j]; v[3] = b_rgb1[j];
            }
            rec.v = pack8(v); tbl[(R_R1B+t)*64 + lane] = rec.u;
        }
    } else if (wid == 2) {
        #pragma unroll
        for (int c = 0; c < 4; ++c) {        // Ar2: rows m=0..2 rgb; k=hh=16c+rr
            float v[8];
            #pragma unroll
            for (int q = 0; q < 8; ++q) {
                const int hh = 16*c + (q&3) + 8*(q>>2) + 4*h;
                v[q] = (m < 3) ? w_rgb2[hh*3 + m] : 0.0f;
            }
            rec.v = pack8(v); tbl[(R_AR2+c)*64 + lane] = rec.u;
        }
        #pragma unroll
        for (int c = 0; c < 2; ++c) {        // Ar2f: w_sigma on row m=3; k=f=16c+rr
            float v[8];
            #pragma unroll
            for (int q = 0; q < 8; ++q) {
                const int f = 16*c + (q&3) + 8*(q>>2) + 4*h;
                v[q] = (m == 3) ? w_sigma[f] : 0.0f;
            }
            rec.v = pack8(v); tbl[(R_AR2F+c)*64 + lane] = rec.u;
        }
        Rec16U r16;
        #pragma unroll
        for (int i = 0; i < 4; ++i) {        // b2i: C-init, reg=4i+e -> b2[e+8i+4h]
            #pragma unroll
            for (int e = 0; e < 4; ++e) r16.f[4*i+e] = b2[e + 8*i + 4*h];
        }
        #pragma unroll
        for (int i = 0; i < 4; ++i) tbl[(R_B2I+i)*64 + lane] = r16.u[i];
        #pragma unroll
        for (int i = 0; i < 4; ++i) {        // arinit: row r=e+8i+4h
            #pragma unroll
            for (int e = 0; e < 4; ++e) {
                const int r = e + 8*i + 4*h;
                r16.f[4*i+e] = (r < 3) ? b_rgb2[r] : ((r == 3) ? b_sigma[0] : 0.0f);
            }
        }
        #pragma unroll
        for (int i = 0; i < 4; ++i) tbl[(R_ARI+i)*64 + lane] = r16.u[i];
    }
}

// ---------------------------------------------------------------------------
// Main MFMA MLP, 32x32x16 shape: one wave = 8 sequential 32-sample tiles.
// 18 MFMAs / 32 samples (vs 38 with 16x16). All boundaries in-register:
// B[kstep c] element q = acc reg (q + 8*(c&1)) of tile (c>>1).
// ---------------------------------------------------------------------------
__global__ __launch_bounds__(256, 2) void nerf_mlp_mfma(
    const float* __restrict__ samples,   // (N_SAMPLES, 7)
    const uint4* __restrict__ tbl,       // [26][64] frag table
    float4* __restrict__ out)            // (N_SAMPLES): tau, r, g, b
{
    const int lane = threadIdx.x & 63;
    const int m32  = lane & 31;
    const int h    = lane >> 5;
    const int wgid = (blockIdx.x * blockDim.x + threadIdx.x) >> 6;  // 0..4095
    const int base0 = wgid * 256;        // 8 tiles x 32 samples

    // ---- tile-0 sample loads first (2-deep rotating buffers)
    f4a sa[2], sb[2];
    {
        const float* sp = samples + (size_t)(base0 + m32) * 7;
        sa[0] = *(const f4a*)sp;  sb[0] = *(const f4a*)(sp + 3);
    }

    // ---- coalesced fragment loads
    bf16x8 A1[2], A2[4], R1a[4], R1b[2], Ar2[4], Ar2f[2];
    f32x16 b2i, arinit;
    {
        RecU r_;
        #pragma unroll
        for (int t = 0; t < 2; ++t) { r_.u = tbl[(R_A1+t)*64 + lane];  A1[t]  = r_.v; }
        #pragma unroll
        for (int c = 0; c < 4; ++c) { r_.u = tbl[(R_A2+c)*64 + lane];  A2[c]  = r_.v; }
        #pragma unroll
        for (int i = 0; i < 4; ++i) { r_.u = tbl[(R_R1A+i)*64 + lane]; R1a[i] = r_.v; }
        #pragma unroll
        for (int t = 0; t < 2; ++t) { r_.u = tbl[(R_R1B+t)*64 + lane]; R1b[t] = r_.v; }
        #pragma unroll
        for (int c = 0; c < 4; ++c) { r_.u = tbl[(R_AR2+c)*64 + lane]; Ar2[c] = r_.v; }
        #pragma unroll
        for (int c = 0; c < 2; ++c) { r_.u = tbl[(R_AR2F+c)*64 + lane]; Ar2f[c] = r_.v; }
        Rec16U r16;
        #pragma unroll
        for (int i = 0; i < 4; ++i) r16.u[i] = tbl[(R_B2I+i)*64 + lane];
        b2i = r16.v;
        #pragma unroll
        for (int i = 0; i < 4; ++i) r16.u[i] = tbl[(R_ARI+i)*64 + lane];
        arinit = r16.v;
    }

    const f32x16 zero16 = {0,0,0,0,0,0,0,0,0,0,0,0,0,0,0,0};

    #pragma unroll
    for (int it = 0; it < 8; ++it) {
        const int cb = it & 1;
        const int nb = (it + 1) & 1;
        if (it < 7) {
            const float* sp = samples + (size_t)(base0 + (it + 1) * 32 + m32) * 7;
            sa[nb] = *(const f4a*)sp;  sb[nb] = *(const f4a*)(sp + 3);
        }

        // merged input kstep: h=0 lanes pos+1, h=1 lanes dirs+1 (q4-7 unused)
        FragU bin;
        bin.h2[0] = pk2(h ? sb[cb].x : sa[cb].x, h ? sb[cb].y : sa[cb].y);
        bin.h2[1] = pk2(h ? sb[cb].z : sa[cb].z, 1.0f);
        bin.w[2] = 0; bin.w[3] = 0;

        // layer1: h1 = relu(W1aug^T . in), M=64 -> 2 tiles
        f32x16 accL1[2];
        #pragma unroll
        for (int t = 0; t < 2; ++t)
            accL1[t] = __builtin_amdgcn_mfma_f32_32x32x16_bf16(A1[t], bin.v, zero16, 0,0,0);

        bf16x8 B2c[4];
        B2c[0] = packB_relu<0>(accL1[0]);
        B2c[1] = packB_relu<8>(accL1[0]);
        B2c[2] = packB_relu<0>(accL1[1]);
        B2c[3] = packB_relu<8>(accL1[1]);

        // layer2: feats = W2^T . h1 + b2 (C-init), K=64 -> 4 ksteps
        f32x16 accL2;
        accL2 = __builtin_amdgcn_mfma_f32_32x32x16_bf16(A2[0], B2c[0], b2i, 0,0,0);
        accL2 = __builtin_amdgcn_mfma_f32_32x32x16_bf16(A2[1], B2c[1], accL2, 0,0,0);
        accL2 = __builtin_amdgcn_mfma_f32_32x32x16_bf16(A2[2], B2c[2], accL2, 0,0,0);
        accL2 = __builtin_amdgcn_mfma_f32_32x32x16_bf16(A2[3], B2c[3], accL2, 0,0,0);

        bf16x8 Bf[2];
        Bf[0] = packB_plain<0>(accL2);
        Bf[1] = packB_plain<8>(accL2);

        // rgb1: h = relu(Wr1a^T.feats + Wr1b^T.[dirs;1]), M=64 -> 2 tiles
        f32x16 ah[2];
        #pragma unroll
        for (int t = 0; t < 2; ++t) {
            ah[t] = __builtin_amdgcn_mfma_f32_32x32x16_bf16(R1a[2*t+0], Bf[0], zero16, 0,0,0);
            ah[t] = __builtin_amdgcn_mfma_f32_32x32x16_bf16(R1a[2*t+1], Bf[1], ah[t], 0,0,0);
            ah[t] = __builtin_amdgcn_mfma_f32_32x32x16_bf16(R1b[t],     bin.v, ah[t], 0,0,0);
        }

        bf16x8 Bh[4];
        Bh[0] = packB_relu<0>(ah[0]);
        Bh[1] = packB_relu<8>(ah[0]);
        Bh[2] = packB_relu<0>(ah[1]);
        Bh[3] = packB_relu<8>(ah[1]);

        // rgb2 rows 0-2 + sigma row 3, biases via C-init
        f32x16 ar;
        ar = __builtin_amdgcn_mfma_f32_32x32x16_bf16(Ar2[0], Bh[0], arinit, 0,0,0);
        ar = __builtin_amdgcn_mfma_f32_32x32x16_bf16(Ar2[1], Bh[1], ar, 0,0,0);
        ar = __builtin_amdgcn_mfma_f32_32x32x16_bf16(Ar2[2], Bh[2], ar, 0,0,0);
        ar = __builtin_amdgcn_mfma_f32_32x32x16_bf16(Ar2[3], Bh[3], ar, 0,0,0);
        ar = __builtin_amdgcn_mfma_f32_32x32x16_bf16(Ar2f[0], Bf[0], ar, 0,0,0);
        ar = __builtin_amdgcn_mfma_f32_32x32x16_bf16(Ar2f[1], Bf[1], ar, 0,0,0);

        // rows 0-3 live in regs 0-3 of h=0 lanes (col = sample = lane&31)
        const float rr    = sigmoid_fast(ar[0]);
        const float gg    = sigmoid_fast(ar[1]);
        const float bb    = sigmoid_fast(ar[2]);
        const float sigma = softplus_fast(ar[3]);
        const float tau   = sigma * sb[cb].w;
        if (lane < 32) out[base0 + it * 32 + m32] = make_float4(tau, rr, gg, bb);
    }
}

// ---------------------------------------------------------------------------
// Kernel 2: one wave per ray — scan tau, gate, reduce.
// ---------------------------------------------------------------------------
__global__ __launch_bounds__(256) void nerf_render_kernel(
    const float4* __restrict__ smp,
    const int*    __restrict__ packing,
    const float*  __restrict__ bg,
    float*        __restrict__ out)
{
    const int gtid = blockIdx.x * blockDim.x + threadIdx.x;
    const int ray  = gtid >> 6;
    const int lane = threadIdx.x & 63;
    if (ray >= N_RAYS) return;

    const int start = packing[2 * ray];
    const int count = packing[2 * ray + 1];

    float tau = 0.0f, r = 0.0f, g = 0.0f, b = 0.0f;
    if (lane < count) {
        const float4 v = smp[start + lane];
        tau = v.x; r = v.y; g = v.z; b = v.w;
    }

    float incl = tau;
    #pragma unroll
    for (int off = 1; off < 64; off <<= 1) {
        const float v = __shfl_up(incl, off, 64);
        if (lane >= off) incl += v;
    }
    const float c_excl = incl - tau;

    const float T     = __expf(-c_excl);
    const float alpha = 1.0f - __expf(-tau);
    float w = (lane < count && T > THRESH) ? T * alpha : 0.0f;

    float cr = r * w, cg = g * w, cb = b * w;

    #pragma unroll
    for (int off = 32; off > 0; off >>= 1) {
        cr += __shfl_down(cr, off, 64);
        cg += __shfl_down(cg, off, 64);
        cb += __shfl_down(cb, off, 64);
        w  += __shfl_down(w,  off, 64);
    }

    if (lane == 0) {
        out[ray * 3 + 0] = cr + bg[0] * (1.0f - w);
        out[ray * 3 + 1] = cg + bg[1] * (1.0f - w);
        out[ray * 3 + 2] = cb + bg[2] * (1.0f - w);
    }
}

extern "C" void kernel_launch(void* const* d_in, const int* in_sizes, int n_in,
                              void* d_out, int out_size, void* d_ws, size_t ws_size,
                              hipStream_t stream) {
    const float* samples  = (const float*)d_in[0];
    const int*   packing  = (const int*)  d_in[1];
    const float* w1       = (const float*)d_in[3];
    const float* b1       = (const float*)d_in[4];
    const float* w2       = (const float*)d_in[5];
    const float* b2       = (const float*)d_in[6];
    const float* w_sigma  = (const float*)d_in[7];
    const float* b_sigma  = (const float*)d_in[8];
    const float* w_rgb1   = (const float*)d_in[9];
    const float* b_rgb1   = (const float*)d_in[10];
    const float* w_rgb2   = (const float*)d_in[11];
    const float* b_rgb2   = (const float*)d_in[12];
    const float* bg       = (const float*)d_in[13];

    float4* smp = (float4*)d_ws;                         // 16 MiB
    uint4*  tbl = (uint4*)((char*)d_ws + TBL_OFF);       // 26x64x16B frag table
    float*  out = (float*)d_out;

    nerf_build_frags<<<1, 256, 0, stream>>>(
        w1, b1, w2, b2, w_sigma, b_sigma,
        w_rgb1, b_rgb1, w_rgb2, b_rgb2, tbl);

    // 1024 blocks x 4 waves = 4096 waves x 8 tiles x 32 samples = N_SAMPLES
    nerf_mlp_mfma<<<1024, 256, 0, stream>>>(samples, tbl, (float4*)smp);

    nerf_render_kernel<<<(N_RAYS * 64) / 256, 256, 0, stream>>>(smp, packing, bg, out);
}

// Round 13
// 46.488 us; speedup vs baseline: 1.2996x; 1.0226x over previous
//
#include <hip/hip_runtime.h>
#include <hip/hip_bf16.h>
#include <math.h>
#include <stdint.h>

#define N_RAYS    32768
#define N_SAMPLES (N_RAYS * 32)
#define THRESH 0.0001f
#define TBL_OFF  (16u * 1024u * 1024u)   // frag table after smp[] in d_ws

// record ids in frag table (one uint4 per lane per record)
#define R_A1   0   // +t (2)
#define R_A2   2   // +c (4)
#define R_R1A  6   // +2t+c (4)
#define R_R1B  10  // +t (2)
#define R_AR2  12  // +c (4)
#define R_AR2F 16  // +c (2)
#define R_B2I  18  // +i (4)
#define R_ARI  22  // +i (4)   -> 26 records total

typedef __attribute__((ext_vector_type(8)))  __bf16 bf16x8;
typedef __attribute__((ext_vector_type(16))) float  f32x16;
typedef float f4a __attribute__((ext_vector_type(4), aligned(4)));

union FragU  { __hip_bfloat162 h2[4]; uint32_t w[4]; bf16x8 v; };
union RecU   { bf16x8 v; uint4 u; };
union Rec16U { f32x16 v; uint4 u[4]; float f[16]; };

__device__ inline __hip_bfloat162 pk2(float lo, float hi) {
    float2 t; t.x = lo; t.y = hi;
    return __float22bfloat162_rn(t);
}

__device__ inline bf16x8 pack8(const float* vals) {
    FragU u;
    u.h2[0] = pk2(vals[0], vals[1]);
    u.h2[1] = pk2(vals[2], vals[3]);
    u.h2[2] = pk2(vals[4], vals[5]);
    u.h2[3] = pk2(vals[6], vals[7]);
    return u.v;
}

__device__ inline float rcp_fast(float x) {
    float r;
    asm("v_rcp_f32 %0, %1" : "=v"(r) : "v"(x));
    return r;
}
__device__ inline float sigmoid_fast(float x) { return rcp_fast(1.0f + __expf(-x)); }
__device__ inline float softplus_fast(float x) {
    const float e = __expf(-fabsf(x));
    return fmaxf(x, 0.0f) + __logf(1.0f + e);
}

// B-fragment from accumulator: element q = acc[P + q], optionally relu'd.
template <int P>
__device__ inline bf16x8 packB_relu(f32x16 a) {
    FragU u;
    u.h2[0] = pk2(fmaxf(a[P+0],0.f), fmaxf(a[P+1],0.f));
    u.h2[1] = pk2(fmaxf(a[P+2],0.f), fmaxf(a[P+3],0.f));
    u.h2[2] = pk2(fmaxf(a[P+4],0.f), fmaxf(a[P+5],0.f));
    u.h2[3] = pk2(fmaxf(a[P+6],0.f), fmaxf(a[P+7],0.f));
    return u.v;
}
template <int P>
__device__ inline bf16x8 packB_plain(f32x16 a) {
    FragU u;
    u.h2[0] = pk2(a[P+0], a[P+1]);
    u.h2[1] = pk2(a[P+2], a[P+3]);
    u.h2[2] = pk2(a[P+4], a[P+5]);
    u.h2[3] = pk2(a[P+6], a[P+7]);
    return u.v;
}

// ---------------------------------------------------------------------------
// Setup kernel: per-lane weight fragments for the 32x32x16 path (unchanged
// from round 12 — layout verified). D layout: col=lane&31,
// row=(reg&3)+8*(reg>>2)+4*(lane>>5);  rr(q,h) = (q&3)+8*(q>>2)+4*h.
// ---------------------------------------------------------------------------
__global__ __launch_bounds__(256) void nerf_build_frags(
    const float* __restrict__ w1,  const float* __restrict__ b1,
    const float* __restrict__ w2,  const float* __restrict__ b2,
    const float* __restrict__ w_sigma, const float* __restrict__ b_sigma,
    const float* __restrict__ w_rgb1,  const float* __restrict__ b_rgb1,
    const float* __restrict__ w_rgb2,  const float* __restrict__ b_rgb2,
    uint4* __restrict__ tbl)
{
    const int wid  = threadIdx.x >> 6;
    const int lane = threadIdx.x & 63;
    const int m    = lane & 31;
    const int h    = lane >> 5;
    RecU rec;

    if (wid == 0) {
        #pragma unroll
        for (int t = 0; t < 2; ++t) {        // A1: rows j=32t+m; k slots h=0,q0..3
            float v[8] = {0,0,0,0,0,0,0,0};
            if (h == 0) {
                const int j = 32*t + m;
                v[0] = w1[j]; v[1] = w1[64+j]; v[2] = w1[128+j]; v[3] = b1[j];
            }
            rec.v = pack8(v); tbl[(R_A1+t)*64 + lane] = rec.u;
        }
        #pragma unroll
        for (int c = 0; c < 4; ++c) {        // A2: A[f=m][j=16c+rr(q,h)] = w2[j*32+f]
            float v[8];
            #pragma unroll
            for (int q = 0; q < 8; ++q) {
                const int j = 16*c + (q&3) + 8*(q>>2) + 4*h;
                v[q] = w2[j*32 + m];
            }
            rec.v = pack8(v); tbl[(R_A2+c)*64 + lane] = rec.u;
        }
    } else if (wid == 1) {
        #pragma unroll
        for (int t = 0; t < 2; ++t)          // Ar1a: rows j=32t+m; k=f=16c+rr
            #pragma unroll
            for (int c = 0; c < 2; ++c) {
                float v[8];
                #pragma unroll
                for (int q = 0; q < 8; ++q) {
                    const int f = 16*c + (q&3) + 8*(q>>2) + 4*h;
                    v[q] = w_rgb1[f*64 + 32*t + m];
                }
                rec.v = pack8(v); tbl[(R_R1A+2*t+c)*64 + lane] = rec.u;
            }
        #pragma unroll
        for (int t = 0; t < 2; ++t) {        // Ar1b: dirs+bias on h=1 slots q0..3
            float v[8] = {0,0,0,0,0,0,0,0};
            if (h == 1) {
                const int j = 32*t + m;
                v[0] = w_rgb1[32*64 + j]; v[1] = w_rgb1[33*64 + j];
                v[2] = w_rgb1[34*64 + j]; v[3] = b_rgb1[j];
            }
            rec.v = pack8(v); tbl[(R_R1B+t)*64 + lane] = rec.u;
        }
    } else if (wid == 2) {
        #pragma unroll
        for (int c = 0; c < 4; ++c) {        // Ar2: rows m=0..2 rgb; k=hh=16c+rr
            float v[8];
            #pragma unroll
            for (int q = 0; q < 8; ++q) {
                const int hh = 16*c + (q&3) + 8*(q>>2) + 4*h;
                v[q] = (m < 3) ? w_rgb2[hh*3 + m] : 0.0f;
            }
            rec.v = pack8(v); tbl[(R_AR2+c)*64 + lane] = rec.u;
        }
        #pragma unroll
        for (int c = 0; c < 2; ++c) {        // Ar2f: w_sigma on row m=3; k=f=16c+rr
            float v[8];
            #pragma unroll
            for (int q = 0; q < 8; ++q) {
                const int f = 16*c + (q&3) + 8*(q>>2) + 4*h;
                v[q] = (m == 3) ? w_sigma[f] : 0.0f;
            }
            rec.v = pack8(v); tbl[(R_AR2F+c)*64 + lane] = rec.u;
        }
        Rec16U r16;
        #pragma unroll
        for (int i = 0; i < 4; ++i) {        // b2i: C-init, reg=4i+e -> b2[e+8i+4h]
            #pragma unroll
            for (int e = 0; e < 4; ++e) r16.f[4*i+e] = b2[e + 8*i + 4*h];
        }
        #pragma unroll
        for (int i = 0; i < 4; ++i) tbl[(R_B2I+i)*64 + lane] = r16.u[i];
        #pragma unroll
        for (int i = 0; i < 4; ++i) {        // arinit: row r=e+8i+4h
            #pragma unroll
            for (int e = 0; e < 4; ++e) {
                const int r = e + 8*i + 4*h;
                r16.f[4*i+e] = (r < 3) ? b_rgb2[r] : ((r == 3) ? b_sigma[0] : 0.0f);
            }
        }
        #pragma unroll
        for (int i = 0; i < 4; ++i) tbl[(R_ARI+i)*64 + lane] = r16.u[i];
    }
}

// ---------------------------------------------------------------------------
// Main MFMA MLP, 32x32x16, DUAL-STREAM: one wave = 4 pairs of independent
// 32-sample tiles, lock-step interleaved. 2 waves/SIMD x 2 chains = 4
// independent MFMA dependency chains per SIMD (the round-12 model says the
// kernel is dependent-chain latency-bound at 2 waves x 1 chain).
// ---------------------------------------------------------------------------
__global__ __launch_bounds__(256, 2) void nerf_mlp_mfma(
    const float* __restrict__ samples,   // (N_SAMPLES, 7)
    const uint4* __restrict__ tbl,       // [26][64] frag table
    float4* __restrict__ out)            // (N_SAMPLES): tau, r, g, b
{
    const int lane = threadIdx.x & 63;
    const int m32  = lane & 31;
    const int h    = lane >> 5;
    const int wgid = (blockIdx.x * blockDim.x + threadIdx.x) >> 6;  // 0..4095
    const int base0 = wgid * 256;        // 4 pairs x 64 samples

    // ---- pair-0 sample loads first (2-deep rotating buffers)
    f4a sa[2][2], sb[2][2];
    {
        const float* sp0 = samples + (size_t)(base0 + m32) * 7;
        const float* sp1 = samples + (size_t)(base0 + 32 + m32) * 7;
        sa[0][0] = *(const f4a*)sp0;  sb[0][0] = *(const f4a*)(sp0 + 3);
        sa[0][1] = *(const f4a*)sp1;  sb[0][1] = *(const f4a*)(sp1 + 3);
    }

    // ---- coalesced fragment loads
    bf16x8 A1[2], A2[4], R1a[4], R1b[2], Ar2[4], Ar2f[2];
    f32x16 b2i, arinit;
    {
        RecU r_;
        #pragma unroll
        for (int t = 0; t < 2; ++t) { r_.u = tbl[(R_A1+t)*64 + lane];  A1[t]  = r_.v; }
        #pragma unroll
        for (int c = 0; c < 4; ++c) { r_.u = tbl[(R_A2+c)*64 + lane];  A2[c]  = r_.v; }
        #pragma unroll
        for (int i = 0; i < 4; ++i) { r_.u = tbl[(R_R1A+i)*64 + lane]; R1a[i] = r_.v; }
        #pragma unroll
        for (int t = 0; t < 2; ++t) { r_.u = tbl[(R_R1B+t)*64 + lane]; R1b[t] = r_.v; }
        #pragma unroll
        for (int c = 0; c < 4; ++c) { r_.u = tbl[(R_AR2+c)*64 + lane]; Ar2[c] = r_.v; }
        #pragma unroll
        for (int c = 0; c < 2; ++c) { r_.u = tbl[(R_AR2F+c)*64 + lane]; Ar2f[c] = r_.v; }
        Rec16U r16;
        #pragma unroll
        for (int i = 0; i < 4; ++i) r16.u[i] = tbl[(R_B2I+i)*64 + lane];
        b2i = r16.v;
        #pragma unroll
        for (int i = 0; i < 4; ++i) r16.u[i] = tbl[(R_ARI+i)*64 + lane];
        arinit = r16.v;
    }

    const f32x16 zero16 = {0,0,0,0,0,0,0,0,0,0,0,0,0,0,0,0};

    #pragma unroll
    for (int it = 0; it < 4; ++it) {
        const int cb = it & 1;
        const int nb = (it + 1) & 1;
        if (it < 3) {                    // prefetch next pair
            const int nbase = base0 + (it + 1) * 64;
            const float* sp0 = samples + (size_t)(nbase + m32) * 7;
            const float* sp1 = samples + (size_t)(nbase + 32 + m32) * 7;
            sa[nb][0] = *(const f4a*)sp0;  sb[nb][0] = *(const f4a*)(sp0 + 3);
            sa[nb][1] = *(const f4a*)sp1;  sb[nb][1] = *(const f4a*)(sp1 + 3);
        }

        // merged input kstep per stream: h=0 lanes pos+1, h=1 lanes dirs+1
        FragU bin[2];
        #pragma unroll
        for (int s = 0; s < 2; ++s) {
            bin[s].h2[0] = pk2(h ? sb[cb][s].x : sa[cb][s].x,
                               h ? sb[cb][s].y : sa[cb][s].y);
            bin[s].h2[1] = pk2(h ? sb[cb][s].z : sa[cb][s].z, 1.0f);
            bin[s].w[2] = 0; bin[s].w[3] = 0;
        }

        // layer1: 2 tiles x 2 streams (4 independent MFMAs)
        f32x16 accL1[2][2];
        #pragma unroll
        for (int t = 0; t < 2; ++t)
            #pragma unroll
            for (int s = 0; s < 2; ++s)
                accL1[s][t] = __builtin_amdgcn_mfma_f32_32x32x16_bf16(A1[t], bin[s].v, zero16, 0,0,0);

        bf16x8 B2c[2][4];
        #pragma unroll
        for (int s = 0; s < 2; ++s) {
            B2c[s][0] = packB_relu<0>(accL1[s][0]);
            B2c[s][1] = packB_relu<8>(accL1[s][0]);
            B2c[s][2] = packB_relu<0>(accL1[s][1]);
            B2c[s][3] = packB_relu<8>(accL1[s][1]);
        }

        // layer2: 4-kstep chain per stream, streams interleaved
        f32x16 accL2[2];
        #pragma unroll
        for (int s = 0; s < 2; ++s)
            accL2[s] = __builtin_amdgcn_mfma_f32_32x32x16_bf16(A2[0], B2c[s][0], b2i, 0,0,0);
        #pragma unroll
        for (int c = 1; c < 4; ++c)
            #pragma unroll
            for (int s = 0; s < 2; ++s)
                accL2[s] = __builtin_amdgcn_mfma_f32_32x32x16_bf16(A2[c], B2c[s][c], accL2[s], 0,0,0);

        bf16x8 Bf[2][2];
        #pragma unroll
        for (int s = 0; s < 2; ++s) {
            Bf[s][0] = packB_plain<0>(accL2[s]);
            Bf[s][1] = packB_plain<8>(accL2[s]);
        }

        // rgb1: 2 tiles x 2 streams, 3-deep chains interleaved
        f32x16 ah[2][2];
        #pragma unroll
        for (int t = 0; t < 2; ++t)
            #pragma unroll
            for (int s = 0; s < 2; ++s) {
                ah[s][t] = __builtin_amdgcn_mfma_f32_32x32x16_bf16(R1a[2*t+0], Bf[s][0], zero16, 0,0,0);
                ah[s][t] = __builtin_amdgcn_mfma_f32_32x32x16_bf16(R1a[2*t+1], Bf[s][1], ah[s][t], 0,0,0);
                ah[s][t] = __builtin_amdgcn_mfma_f32_32x32x16_bf16(R1b[t],     bin[s].v, ah[s][t], 0,0,0);
            }

        bf16x8 Bh[2][4];
        #pragma unroll
        for (int s = 0; s < 2; ++s) {
            Bh[s][0] = packB_relu<0>(ah[s][0]);
            Bh[s][1] = packB_relu<8>(ah[s][0]);
            Bh[s][2] = packB_relu<0>(ah[s][1]);
            Bh[s][3] = packB_relu<8>(ah[s][1]);
        }

        // rgb2 (+sigma row 3): 6-kstep chain per stream, interleaved
        f32x16 ar[2];
        #pragma unroll
        for (int s = 0; s < 2; ++s)
            ar[s] = __builtin_amdgcn_mfma_f32_32x32x16_bf16(Ar2[0], Bh[s][0], arinit, 0,0,0);
        #pragma unroll
        for (int c = 1; c < 4; ++c)
            #pragma unroll
            for (int s = 0; s < 2; ++s)
                ar[s] = __builtin_amdgcn_mfma_f32_32x32x16_bf16(Ar2[c], Bh[s][c], ar[s], 0,0,0);
        #pragma unroll
        for (int c = 0; c < 2; ++c)
            #pragma unroll
            for (int s = 0; s < 2; ++s)
                ar[s] = __builtin_amdgcn_mfma_f32_32x32x16_bf16(Ar2f[c], Bf[s][c], ar[s], 0,0,0);

        #pragma unroll
        for (int s = 0; s < 2; ++s) {
            const float rr    = sigmoid_fast(ar[s][0]);
            const float gg    = sigmoid_fast(ar[s][1]);
            const float bb    = sigmoid_fast(ar[s][2]);
            const float sigma = softplus_fast(ar[s][3]);
            const float tau   = sigma * sb[cb][s].w;
            if (lane < 32) out[base0 + it * 64 + s * 32 + m32] = make_float4(tau, rr, gg, bb);
        }
    }
}

// ---------------------------------------------------------------------------
// Kernel 2: one wave per ray — scan tau, gate, reduce.
// ---------------------------------------------------------------------------
__global__ __launch_bounds__(256) void nerf_render_kernel(
    const float4* __restrict__ smp,
    const int*    __restrict__ packing,
    const float*  __restrict__ bg,
    float*        __restrict__ out)
{
    const int gtid = blockIdx.x * blockDim.x + threadIdx.x;
    const int ray  = gtid >> 6;
    const int lane = threadIdx.x & 63;
    if (ray >= N_RAYS) return;

    const int start = packing[2 * ray];
    const int count = packing[2 * ray + 1];

    float tau = 0.0f, r = 0.0f, g = 0.0f, b = 0.0f;
    if (lane < count) {
        const float4 v = smp[start + lane];
        tau = v.x; r = v.y; g = v.z; b = v.w;
    }

    float incl = tau;
    #pragma unroll
    for (int off = 1; off < 64; off <<= 1) {
        const float v = __shfl_up(incl, off, 64);
        if (lane >= off) incl += v;
    }
    const float c_excl = incl - tau;

    const float T     = __expf(-c_excl);
    const float alpha = 1.0f - __expf(-tau);
    float w = (lane < count && T > THRESH) ? T * alpha : 0.0f;

    float cr = r * w, cg = g * w, cb = b * w;

    #pragma unroll
    for (int off = 32; off > 0; off >>= 1) {
        cr += __shfl_down(cr, off, 64);
        cg += __shfl_down(cg, off, 64);
        cb += __shfl_down(cb, off, 64);
        w  += __shfl_down(w,  off, 64);
    }

    if (lane == 0) {
        out[ray * 3 + 0] = cr + bg[0] * (1.0f - w);
        out[ray * 3 + 1] = cg + bg[1] * (1.0f - w);
        out[ray * 3 + 2] = cb + bg[2] * (1.0f - w);
    }
}

extern "C" void kernel_launch(void* const* d_in, const int* in_sizes, int n_in,
                              void* d_out, int out_size, void* d_ws, size_t ws_size,
                              hipStream_t stream) {
    const float* samples  = (const float*)d_in[0];
    const int*   packing  = (const int*)  d_in[1];
    const float* w1       = (const float*)d_in[3];
    const float* b1       = (const float*)d_in[4];
    const float* w2       = (const float*)d_in[5];
    const float* b2       = (const float*)d_in[6];
    const float* w_sigma  = (const float*)d_in[7];
    const float* b_sigma  = (const float*)d_in[8];
    const float* w_rgb1   = (const float*)d_in[9];
    const float* b_rgb1   = (const float*)d_in[10];
    const float* w_rgb2   = (const float*)d_in[11];
    const float* b_rgb2   = (const float*)d_in[12];
    const float* bg       = (const float*)d_in[13];

    float4* smp = (float4*)d_ws;                         // 16 MiB
    uint4*  tbl = (uint4*)((char*)d_ws + TBL_OFF);       // 26x64x16B frag table
    float*  out = (float*)d_out;

    nerf_build_frags<<<1, 256, 0, stream>>>(
        w1, b1, w2, b2, w_sigma, b_sigma,
        w_rgb1, b_rgb1, w_rgb2, b_rgb2, tbl);

    // 1024 blocks x 4 waves = 4096 waves x 4 pairs x 64 samples = N_SAMPLES
    nerf_mlp_mfma<<<1024, 256, 0, stream>>>(samples, tbl, (float4*)smp);

    nerf_render_kernel<<<(N_RAYS * 64) / 256, 256, 0, stream>>>(smp, packing, bg, out);
}